// Round 1
// baseline (1179.466 us; speedup 1.0000x reference)
//
#include <hip/hip_runtime.h>

#define D_MODEL 384
#define D_STATE 16
#define D_INNER 768
#define DT_RANK 24
#define NB 8
#define LSEQ 1024
#define NROWS (NB * LSEQ)            // 8192
#define XZ_N (2 * D_INNER)           // 1536
#define DBC_N (DT_RANK + 2 * D_STATE) // 56

// ---------------- GEMM1: xz[m][j] = sum_c xseq[m][c] * in_proj_w[j][c]
// A[m][k] = x[b][k][l]  (K-major in memory, contiguous in l=m&1023)
__global__ __launch_bounds__(256) void k_inproj(const float* __restrict__ x,
                                                const float* __restrict__ W,
                                                float* __restrict__ xz) {
    __shared__ float As[16][64];
    __shared__ float Bs[16][64];
    const int n0 = blockIdx.x * 64;
    const int m0 = blockIdx.y * 64;
    const int b  = m0 >> 10;
    const int l0 = m0 & 1023;
    const int t  = threadIdx.x;
    const int tx = t & 15, ty = t >> 4;
    const int kkA = t >> 4, mmA = (t & 15) * 4;     // A: As[kkA][mmA..+3]
    const int nnB = t >> 2, kkB = (t & 3) * 4;      // B: W[n0+nnB][k0+kkB..+3]
    float acc[4][4] = {};
    for (int k0 = 0; k0 < D_MODEL; k0 += 16) {
        const float4 av = *reinterpret_cast<const float4*>(
            &x[(size_t)b * D_MODEL * LSEQ + (size_t)(k0 + kkA) * LSEQ + l0 + mmA]);
        *reinterpret_cast<float4*>(&As[kkA][mmA]) = av;
        const float4 bv = *reinterpret_cast<const float4*>(
            &W[(size_t)(n0 + nnB) * D_MODEL + k0 + kkB]);
        Bs[kkB + 0][nnB] = bv.x; Bs[kkB + 1][nnB] = bv.y;
        Bs[kkB + 2][nnB] = bv.z; Bs[kkB + 3][nnB] = bv.w;
        __syncthreads();
#pragma unroll
        for (int kk = 0; kk < 16; ++kk) {
            float a[4], bb[4];
#pragma unroll
            for (int i = 0; i < 4; ++i) a[i] = As[kk][ty * 4 + i];
#pragma unroll
            for (int j = 0; j < 4; ++j) bb[j] = Bs[kk][tx * 4 + j];
#pragma unroll
            for (int i = 0; i < 4; ++i)
#pragma unroll
                for (int j = 0; j < 4; ++j)
                    acc[i][j] = fmaf(a[i], bb[j], acc[i][j]);
        }
        __syncthreads();
    }
#pragma unroll
    for (int i = 0; i < 4; ++i) {
        float4 v = make_float4(acc[i][0], acc[i][1], acc[i][2], acc[i][3]);
        *reinterpret_cast<float4*>(&xz[(size_t)(m0 + ty * 4 + i) * XZ_N + n0 + tx * 4]) = v;
    }
}

// ---------------- conv (causal, 3 taps) + SiLU -> u[row][d]
__global__ __launch_bounds__(256) void k_conv(const float* __restrict__ xz,
                                              const float* __restrict__ cw,
                                              const float* __restrict__ cb,
                                              float* __restrict__ u) {
    const int i = blockIdx.x * 256 + threadIdx.x;   // over NROWS*D_INNER, d fastest
    const int d = i % D_INNER;
    const int row = i / D_INNER;
    const int l = row & 1023;
    float acc = cb[d];
    const float w0 = cw[d * 3 + 0], w1 = cw[d * 3 + 1], w2 = cw[d * 3 + 2];
    if (l >= 2) acc = fmaf(xz[(size_t)(row - 2) * XZ_N + d], w0, acc);
    if (l >= 1) acc = fmaf(xz[(size_t)(row - 1) * XZ_N + d], w1, acc);
    acc = fmaf(xz[(size_t)row * XZ_N + d], w2, acc);
    u[i] = acc / (1.f + __expf(-acc));
}

// ---------------- x_proj: dbc[row][j] = sum_k u[row][k] * x_proj_w[j][k], j<56
__global__ __launch_bounds__(256) void k_xproj(const float* __restrict__ u,
                                               const float* __restrict__ W,
                                               float* __restrict__ dbc) {
    __shared__ float us[4][D_INNER];
    const int w = threadIdx.x >> 6;
    const int lane = threadIdx.x & 63;
    const int row = blockIdx.x * 4 + w;
#pragma unroll
    for (int it = 0; it < 3; ++it) {
        const int k = it * 256 + lane * 4;
        *reinterpret_cast<float4*>(&us[w][k]) =
            *reinterpret_cast<const float4*>(&u[(size_t)row * D_INNER + k]);
    }
    __syncthreads();
    if (lane < DBC_N) {
        float acc = 0.f;
        for (int k = 0; k < D_INNER; k += 4) {
            const float4 wv = *reinterpret_cast<const float4*>(&W[(size_t)lane * D_INNER + k]);
            acc = fmaf(us[w][k + 0], wv.x, acc);
            acc = fmaf(us[w][k + 1], wv.y, acc);
            acc = fmaf(us[w][k + 2], wv.z, acc);
            acc = fmaf(us[w][k + 3], wv.w, acc);
        }
        dbc[(size_t)row * DBC_N + lane] = acc;
    }
}

// ---------------- dt_proj (K=24) + softplus -> dt[row][d]
__global__ __launch_bounds__(256) void k_dtproj(const float* __restrict__ dbc,
                                                const float* __restrict__ W,
                                                const float* __restrict__ bias,
                                                float* __restrict__ dt) {
    __shared__ float s[64 * DT_RANK];
    const int d = blockIdx.x * 256 + threadIdx.x;   // gridDim.x = 3
    const int r0 = blockIdx.y * 64;
    float wr[DT_RANK];
#pragma unroll
    for (int q = 0; q < DT_RANK; q += 4) {
        const float4 wv = *reinterpret_cast<const float4*>(&W[(size_t)d * DT_RANK + q]);
        wr[q] = wv.x; wr[q + 1] = wv.y; wr[q + 2] = wv.z; wr[q + 3] = wv.w;
    }
    const float bv = bias[d];
    for (int e = threadIdx.x; e < 64 * DT_RANK; e += 256) {
        const int rl = e / DT_RANK, rr = e % DT_RANK;
        s[e] = dbc[(size_t)(r0 + rl) * DBC_N + rr];
    }
    __syncthreads();
    for (int rl = 0; rl < 64; ++rl) {
        float acc = bv;
#pragma unroll
        for (int r = 0; r < DT_RANK; ++r) acc = fmaf(s[rl * DT_RANK + r], wr[r], acc);
        dt[(size_t)(r0 + rl) * D_INNER + d] = (acc > 20.f) ? acc : log1pf(__expf(acc));
    }
}

// ---------------- selective scan; fuses +u*D and *silu(z).
// y is written into the SAME buffer as dt (same-wave read-before-write),
// so dty is deliberately NOT __restrict__.
__global__ __launch_bounds__(256) void k_scan(float* dty,
                                              const float* __restrict__ u,
                                              const float* __restrict__ dbc,
                                              const float* __restrict__ xz,
                                              const float* __restrict__ A_log,
                                              const float* __restrict__ Dp) {
    const int t = threadIdx.x;
    const int n = t & 15;
    const int dg = t >> 4;                        // 0..15
    const int b = blockIdx.x / 48;
    const int d = (blockIdx.x % 48) * 16 + dg;
    const float Aval = -__expf(A_log[d * D_STATE + n]);
    const float Dv = Dp[d];
    float h = 0.f;
    const size_t rowbase = (size_t)b * LSEQ;
    for (int l = 0; l < LSEQ; ++l) {
        const size_t row = rowbase + l;
        const float dt_v = dty[row * D_INNER + d];
        const float u_v = u[row * D_INNER + d];
        const float Bv = dbc[row * DBC_N + DT_RANK + n];
        const float Cv = dbc[row * DBC_N + DT_RANK + D_STATE + n];
        const float dA = __expf(dt_v * Aval);
        h = fmaf(dA, h, dt_v * u_v * Bv);
        float p = h * Cv;
        p += __shfl_xor(p, 1);
        p += __shfl_xor(p, 2);
        p += __shfl_xor(p, 4);
        p += __shfl_xor(p, 8);
        if (n == 0) {
            const float zv = xz[row * XZ_N + D_INNER + d];
            const float sz = zv / (1.f + __expf(-zv));
            dty[row * D_INNER + d] = (p + u_v * Dv) * sz;
        }
    }
}

// ---------------- GEMM3: out[b][c][l] = sum_d y[m][d] * out_proj_w[c][d]
__global__ __launch_bounds__(256) void k_outproj(const float* __restrict__ y,
                                                 const float* __restrict__ W,
                                                 float* __restrict__ out) {
    __shared__ float As[16][64];
    __shared__ float Bs[16][64];
    const int n0 = blockIdx.x * 64;   // c
    const int m0 = blockIdx.y * 64;   // row
    const int b  = m0 >> 10;
    const int l0 = m0 & 1023;
    const int t  = threadIdx.x;
    const int tx = t & 15, ty = t >> 4;
    const int rA = t >> 2, kA = (t & 3) * 4;
    float acc[4][4] = {};   // [i=m][j=n]
    for (int k0 = 0; k0 < D_INNER; k0 += 16) {
        const float4 av = *reinterpret_cast<const float4*>(
            &y[(size_t)(m0 + rA) * D_INNER + k0 + kA]);
        As[kA + 0][rA] = av.x; As[kA + 1][rA] = av.y;
        As[kA + 2][rA] = av.z; As[kA + 3][rA] = av.w;
        const float4 bv = *reinterpret_cast<const float4*>(
            &W[(size_t)(n0 + rA) * D_INNER + k0 + kA]);
        Bs[kA + 0][rA] = bv.x; Bs[kA + 1][rA] = bv.y;
        Bs[kA + 2][rA] = bv.z; Bs[kA + 3][rA] = bv.w;
        __syncthreads();
#pragma unroll
        for (int kk = 0; kk < 16; ++kk) {
            float a[4], bb[4];
#pragma unroll
            for (int i = 0; i < 4; ++i) a[i] = As[kk][tx * 4 + i];
#pragma unroll
            for (int j = 0; j < 4; ++j) bb[j] = Bs[kk][ty * 4 + j];
#pragma unroll
            for (int i = 0; i < 4; ++i)
#pragma unroll
                for (int j = 0; j < 4; ++j)
                    acc[i][j] = fmaf(a[i], bb[j], acc[i][j]);
        }
        __syncthreads();
    }
#pragma unroll
    for (int j = 0; j < 4; ++j) {
        float4 v = make_float4(acc[0][j], acc[1][j], acc[2][j], acc[3][j]);
        *reinterpret_cast<float4*>(
            &out[(size_t)b * D_MODEL * LSEQ + (size_t)(n0 + ty * 4 + j) * LSEQ + l0 + tx * 4]) = v;
    }
}

extern "C" void kernel_launch(void* const* d_in, const int* in_sizes, int n_in,
                              void* d_out, int out_size, void* d_ws, size_t ws_size,
                              hipStream_t stream) {
    const float* x         = (const float*)d_in[0];
    const float* in_proj_w = (const float*)d_in[1];
    const float* conv_w    = (const float*)d_in[2];
    const float* conv_b    = (const float*)d_in[3];
    const float* x_proj_w  = (const float*)d_in[4];
    const float* dt_proj_w = (const float*)d_in[5];
    const float* dt_proj_b = (const float*)d_in[6];
    const float* A_log     = (const float*)d_in[7];
    const float* Dp        = (const float*)d_in[8];
    const float* out_proj_w= (const float*)d_in[9];
    float* out = (float*)d_out;

    float* ws  = (float*)d_ws;
    float* xz  = ws;                                   // 8192*1536
    float* u   = xz + (size_t)NROWS * XZ_N;            // 8192*768
    float* dbc = u  + (size_t)NROWS * D_INNER;         // 8192*56
    float* dty = dbc + (size_t)NROWS * DBC_N;          // 8192*768 (dt, then y in-place)

    k_inproj<<<dim3(XZ_N / 64, NROWS / 64), 256, 0, stream>>>(x, in_proj_w, xz);
    k_conv<<<(NROWS * D_INNER) / 256, 256, 0, stream>>>(xz, conv_w, conv_b, u);
    k_xproj<<<NROWS / 4, 256, 0, stream>>>(u, x_proj_w, dbc);
    k_dtproj<<<dim3(3, NROWS / 64), 256, 0, stream>>>(dbc, dt_proj_w, dt_proj_b, dty);
    k_scan<<<NB * 48, 256, 0, stream>>>(dty, u, dbc, xz, A_log, Dp);
    k_outproj<<<dim3(D_MODEL / 64, NROWS / 64), 256, 0, stream>>>(dty, out_proj_w, out);
}

// Round 2
// 658.905 us; speedup vs baseline: 1.7900x; 1.7900x over previous
//
#include <hip/hip_runtime.h>

#define D_MODEL 384
#define D_STATE 16
#define D_INNER 768
#define DT_RANK 24
#define NB 8
#define LSEQ 1024
#define NROWS (NB * LSEQ)            // 8192
#define XZ_N (2 * D_INNER)           // 1536
#define DBC_N (DT_RANK + 2 * D_STATE) // 56
#define CH 64                         // scan chunk (timesteps staged in LDS)

// ---------------- GEMM1: xz[m][j] = sum_c xseq[m][c] * in_proj_w[j][c]
// A[m][k] = x[b][k][l]  (K-major in memory, contiguous in l=m&1023)
__global__ __launch_bounds__(256) void k_inproj(const float* __restrict__ x,
                                                const float* __restrict__ W,
                                                float* __restrict__ xz) {
    __shared__ float As[16][64];
    __shared__ float Bs[16][64];
    const int n0 = blockIdx.x * 64;
    const int m0 = blockIdx.y * 64;
    const int b  = m0 >> 10;
    const int l0 = m0 & 1023;
    const int t  = threadIdx.x;
    const int tx = t & 15, ty = t >> 4;
    const int kkA = t >> 4, mmA = (t & 15) * 4;     // A: As[kkA][mmA..+3]
    const int nnB = t >> 2, kkB = (t & 3) * 4;      // B: W[n0+nnB][k0+kkB..+3]
    float acc[4][4] = {};
    for (int k0 = 0; k0 < D_MODEL; k0 += 16) {
        const float4 av = *reinterpret_cast<const float4*>(
            &x[(size_t)b * D_MODEL * LSEQ + (size_t)(k0 + kkA) * LSEQ + l0 + mmA]);
        *reinterpret_cast<float4*>(&As[kkA][mmA]) = av;
        const float4 bv = *reinterpret_cast<const float4*>(
            &W[(size_t)(n0 + nnB) * D_MODEL + k0 + kkB]);
        Bs[kkB + 0][nnB] = bv.x; Bs[kkB + 1][nnB] = bv.y;
        Bs[kkB + 2][nnB] = bv.z; Bs[kkB + 3][nnB] = bv.w;
        __syncthreads();
#pragma unroll
        for (int kk = 0; kk < 16; ++kk) {
            float a[4], bb[4];
#pragma unroll
            for (int i = 0; i < 4; ++i) a[i] = As[kk][ty * 4 + i];
#pragma unroll
            for (int j = 0; j < 4; ++j) bb[j] = Bs[kk][tx * 4 + j];
#pragma unroll
            for (int i = 0; i < 4; ++i)
#pragma unroll
                for (int j = 0; j < 4; ++j)
                    acc[i][j] = fmaf(a[i], bb[j], acc[i][j]);
        }
        __syncthreads();
    }
#pragma unroll
    for (int i = 0; i < 4; ++i) {
        float4 v = make_float4(acc[i][0], acc[i][1], acc[i][2], acc[i][3]);
        *reinterpret_cast<float4*>(&xz[(size_t)(m0 + ty * 4 + i) * XZ_N + n0 + tx * 4]) = v;
    }
}

// ---------------- conv (causal, 3 taps) + SiLU -> u[row][d]
__global__ __launch_bounds__(256) void k_conv(const float* __restrict__ xz,
                                              const float* __restrict__ cw,
                                              const float* __restrict__ cb,
                                              float* __restrict__ u) {
    const int i = blockIdx.x * 256 + threadIdx.x;   // over NROWS*D_INNER, d fastest
    const int d = i % D_INNER;
    const int row = i / D_INNER;
    const int l = row & 1023;
    float acc = cb[d];
    const float w0 = cw[d * 3 + 0], w1 = cw[d * 3 + 1], w2 = cw[d * 3 + 2];
    if (l >= 2) acc = fmaf(xz[(size_t)(row - 2) * XZ_N + d], w0, acc);
    if (l >= 1) acc = fmaf(xz[(size_t)(row - 1) * XZ_N + d], w1, acc);
    acc = fmaf(xz[(size_t)row * XZ_N + d], w2, acc);
    u[i] = acc / (1.f + __expf(-acc));
}

// ---------------- x_proj: dbc[row][j] = sum_k u[row][k] * x_proj_w[j][k], j<56
__global__ __launch_bounds__(256) void k_xproj(const float* __restrict__ u,
                                               const float* __restrict__ W,
                                               float* __restrict__ dbc) {
    __shared__ float us[4][D_INNER];
    const int w = threadIdx.x >> 6;
    const int lane = threadIdx.x & 63;
    const int row = blockIdx.x * 4 + w;
#pragma unroll
    for (int it = 0; it < 3; ++it) {
        const int k = it * 256 + lane * 4;
        *reinterpret_cast<float4*>(&us[w][k]) =
            *reinterpret_cast<const float4*>(&u[(size_t)row * D_INNER + k]);
    }
    __syncthreads();
    if (lane < DBC_N) {
        float acc = 0.f;
        for (int k = 0; k < D_INNER; k += 4) {
            const float4 wv = *reinterpret_cast<const float4*>(&W[(size_t)lane * D_INNER + k]);
            acc = fmaf(us[w][k + 0], wv.x, acc);
            acc = fmaf(us[w][k + 1], wv.y, acc);
            acc = fmaf(us[w][k + 2], wv.z, acc);
            acc = fmaf(us[w][k + 3], wv.w, acc);
        }
        dbc[(size_t)row * DBC_N + lane] = acc;
    }
}

// ---------------- dt_proj (K=24) + softplus -> dt[row][d]
__global__ __launch_bounds__(256) void k_dtproj(const float* __restrict__ dbc,
                                                const float* __restrict__ W,
                                                const float* __restrict__ bias,
                                                float* __restrict__ dt) {
    __shared__ float s[64 * DT_RANK];
    const int d = blockIdx.x * 256 + threadIdx.x;   // gridDim.x = 3
    const int r0 = blockIdx.y * 64;
    float wr[DT_RANK];
#pragma unroll
    for (int q = 0; q < DT_RANK; q += 4) {
        const float4 wv = *reinterpret_cast<const float4*>(&W[(size_t)d * DT_RANK + q]);
        wr[q] = wv.x; wr[q + 1] = wv.y; wr[q + 2] = wv.z; wr[q + 3] = wv.w;
    }
    const float bv = bias[d];
    for (int e = threadIdx.x; e < 64 * DT_RANK; e += 256) {
        const int rl = e / DT_RANK, rr = e % DT_RANK;
        s[e] = dbc[(size_t)(r0 + rl) * DBC_N + rr];
    }
    __syncthreads();
    for (int rl = 0; rl < 64; ++rl) {
        float acc = bv;
#pragma unroll
        for (int r = 0; r < DT_RANK; ++r) acc = fmaf(s[rl * DT_RANK + r], wr[r], acc);
        dt[(size_t)(r0 + rl) * D_INNER + d] = (acc > 20.f) ? acc : log1pf(__expf(acc));
    }
}

// ---------------- selective scan, LDS-staged chunks of CH timesteps,
// reg-double-buffered (T14 async-split). Fuses +u*D and *silu(z).
// y is written into the SAME buffer as dt (rows of chunk c are fully staged
// in LDS before any y write of chunk c; prefetch of chunk c+1 touches
// disjoint rows), so dty is deliberately NOT __restrict__.
__global__ __launch_bounds__(256) void k_scan(float* dty,
                                              const float* __restrict__ u,
                                              const float* __restrict__ dbc,
                                              const float* __restrict__ xz,
                                              const float* __restrict__ A_log,
                                              const float* __restrict__ Dp) {
    __shared__ float dt_s[CH][16];
    __shared__ float u_s[CH][16];
    __shared__ float z_s[CH][16];
    __shared__ float B_s[CH][16];
    __shared__ float C_s[CH][16];
    const int t = threadIdx.x;
    const int n = t & 15;
    const int dg = t >> 4;                        // 0..15
    const int b = blockIdx.x / 48;
    const int d0 = (blockIdx.x % 48) * 16;
    const int d = d0 + dg;
    const float Aval = -__expf(A_log[d * D_STATE + n]);
    const float Dv = Dp[d];

    // staging role: thread t loads float4 at (lr = t>>2, col = (t&3)*4)
    const int lr = t >> 2;
    const int col = (t & 3) * 4;
    const size_t rowbase = (size_t)b * LSEQ;

    float4 r_dt, r_u, r_z, r_B, r_C;
    {
        const size_t row = rowbase + lr;
        r_dt = *reinterpret_cast<const float4*>(&dty[row * D_INNER + d0 + col]);
        r_u  = *reinterpret_cast<const float4*>(&u  [row * D_INNER + d0 + col]);
        r_z  = *reinterpret_cast<const float4*>(&xz [row * XZ_N + D_INNER + d0 + col]);
        r_B  = *reinterpret_cast<const float4*>(&dbc[row * DBC_N + DT_RANK + col]);
        r_C  = *reinterpret_cast<const float4*>(&dbc[row * DBC_N + DT_RANK + D_STATE + col]);
    }

    float h = 0.f;
    for (int c = 0; c < LSEQ / CH; ++c) {
        __syncthreads();   // previous chunk's LDS reads done
        *reinterpret_cast<float4*>(&dt_s[lr][col]) = r_dt;
        *reinterpret_cast<float4*>(&u_s [lr][col]) = r_u;
        *reinterpret_cast<float4*>(&z_s [lr][col]) = r_z;
        *reinterpret_cast<float4*>(&B_s [lr][col]) = r_B;
        *reinterpret_cast<float4*>(&C_s [lr][col]) = r_C;
        __syncthreads();
        if (c + 1 < LSEQ / CH) {
            const size_t row = rowbase + (c + 1) * CH + lr;
            r_dt = *reinterpret_cast<const float4*>(&dty[row * D_INNER + d0 + col]);
            r_u  = *reinterpret_cast<const float4*>(&u  [row * D_INNER + d0 + col]);
            r_z  = *reinterpret_cast<const float4*>(&xz [row * XZ_N + D_INNER + d0 + col]);
            r_B  = *reinterpret_cast<const float4*>(&dbc[row * DBC_N + DT_RANK + col]);
            r_C  = *reinterpret_cast<const float4*>(&dbc[row * DBC_N + DT_RANK + D_STATE + col]);
        }
        const size_t out_row0 = rowbase + c * CH;
#pragma unroll 4
        for (int l = 0; l < CH; ++l) {
            const float dt_v = dt_s[l][dg];
            const float u_v  = u_s[l][dg];
            const float Bv   = B_s[l][n];
            const float Cv   = C_s[l][n];
            const float dA = __expf(dt_v * Aval);
            h = fmaf(dA, h, dt_v * u_v * Bv);
            float p = h * Cv;
            p += __shfl_xor(p, 1);
            p += __shfl_xor(p, 2);
            p += __shfl_xor(p, 4);
            p += __shfl_xor(p, 8);
            if (n == 0) {
                const float zv = z_s[l][dg];
                const float sz = zv / (1.f + __expf(-zv));
                dty[(out_row0 + l) * D_INNER + d] = (p + u_v * Dv) * sz;
            }
        }
    }
}

// ---------------- GEMM3: out[b][c][l] = sum_d y[m][d] * out_proj_w[c][d]
__global__ __launch_bounds__(256) void k_outproj(const float* __restrict__ y,
                                                 const float* __restrict__ W,
                                                 float* __restrict__ out) {
    __shared__ float As[16][64];
    __shared__ float Bs[16][64];
    const int n0 = blockIdx.x * 64;   // c
    const int m0 = blockIdx.y * 64;   // row
    const int b  = m0 >> 10;
    const int l0 = m0 & 1023;
    const int t  = threadIdx.x;
    const int tx = t & 15, ty = t >> 4;
    const int rA = t >> 2, kA = (t & 3) * 4;
    float acc[4][4] = {};   // [i=m][j=n]
    for (int k0 = 0; k0 < D_INNER; k0 += 16) {
        const float4 av = *reinterpret_cast<const float4*>(
            &y[(size_t)(m0 + rA) * D_INNER + k0 + kA]);
        As[kA + 0][rA] = av.x; As[kA + 1][rA] = av.y;
        As[kA + 2][rA] = av.z; As[kA + 3][rA] = av.w;
        const float4 bv = *reinterpret_cast<const float4*>(
            &W[(size_t)(n0 + rA) * D_INNER + k0 + kA]);
        Bs[kA + 0][rA] = bv.x; Bs[kA + 1][rA] = bv.y;
        Bs[kA + 2][rA] = bv.z; Bs[kA + 3][rA] = bv.w;
        __syncthreads();
#pragma unroll
        for (int kk = 0; kk < 16; ++kk) {
            float a[4], bb[4];
#pragma unroll
            for (int i = 0; i < 4; ++i) a[i] = As[kk][tx * 4 + i];
#pragma unroll
            for (int j = 0; j < 4; ++j) bb[j] = Bs[kk][ty * 4 + j];
#pragma unroll
            for (int i = 0; i < 4; ++i)
#pragma unroll
                for (int j = 0; j < 4; ++j)
                    acc[i][j] = fmaf(a[i], bb[j], acc[i][j]);
        }
        __syncthreads();
    }
#pragma unroll
    for (int j = 0; j < 4; ++j) {
        float4 v = make_float4(acc[0][j], acc[1][j], acc[2][j], acc[3][j]);
        *reinterpret_cast<float4*>(
            &out[(size_t)b * D_MODEL * LSEQ + (size_t)(n0 + ty * 4 + j) * LSEQ + l0 + tx * 4]) = v;
    }
}

extern "C" void kernel_launch(void* const* d_in, const int* in_sizes, int n_in,
                              void* d_out, int out_size, void* d_ws, size_t ws_size,
                              hipStream_t stream) {
    const float* x         = (const float*)d_in[0];
    const float* in_proj_w = (const float*)d_in[1];
    const float* conv_w    = (const float*)d_in[2];
    const float* conv_b    = (const float*)d_in[3];
    const float* x_proj_w  = (const float*)d_in[4];
    const float* dt_proj_w = (const float*)d_in[5];
    const float* dt_proj_b = (const float*)d_in[6];
    const float* A_log     = (const float*)d_in[7];
    const float* Dp        = (const float*)d_in[8];
    const float* out_proj_w= (const float*)d_in[9];
    float* out = (float*)d_out;

    float* ws  = (float*)d_ws;
    float* xz  = ws;                                   // 8192*1536
    float* u   = xz + (size_t)NROWS * XZ_N;            // 8192*768
    float* dbc = u  + (size_t)NROWS * D_INNER;         // 8192*56
    float* dty = dbc + (size_t)NROWS * DBC_N;          // 8192*768 (dt, then y in-place)

    k_inproj<<<dim3(XZ_N / 64, NROWS / 64), 256, 0, stream>>>(x, in_proj_w, xz);
    k_conv<<<(NROWS * D_INNER) / 256, 256, 0, stream>>>(xz, conv_w, conv_b, u);
    k_xproj<<<NROWS / 4, 256, 0, stream>>>(u, x_proj_w, dbc);
    k_dtproj<<<dim3(3, NROWS / 64), 256, 0, stream>>>(dbc, dt_proj_w, dt_proj_b, dty);
    k_scan<<<NB * 48, 256, 0, stream>>>(dty, u, dbc, xz, A_log, Dp);
    k_outproj<<<dim3(D_MODEL / 64, NROWS / 64), 256, 0, stream>>>(dty, out_proj_w, out);
}

// Round 3
// 572.159 us; speedup vs baseline: 2.0614x; 1.1516x over previous
//
#include <hip/hip_runtime.h>

#define D_MODEL 384
#define D_STATE 16
#define D_INNER 768
#define DT_RANK 24
#define NB 8
#define LSEQ 1024
#define NROWS (NB * LSEQ)            // 8192
#define DBC_N 56                     // dbc row stride (only cols 0..23 stored)
#define SEG 16
#define NSEG 64

__device__ __forceinline__ float silu(float x) { return x / (1.f + __expf(-x)); }

// ---------------- GEMM1: in_proj. A[m][k] = x[b][k][l] (K-major, contiguous in l).
// n-tiles 0..11 -> xin row-major [8192][768]; n-tiles 12..23 -> silu(z) transposed szT[b][d][l].
__global__ __launch_bounds__(256) void k_inproj(const float* __restrict__ x,
                                                const float* __restrict__ W,
                                                float* __restrict__ xin,
                                                float* __restrict__ szT) {
    __shared__ float As[16][64];
    __shared__ float Bs[16][64];
    const int n0 = blockIdx.x * 64;            // 0..1535
    const int m0 = blockIdx.y * 64;
    const int b  = m0 >> 10;
    const int l0 = m0 & 1023;
    const int t  = threadIdx.x;
    const int tx = t & 15, ty = t >> 4;
    const int kkA = t >> 4, mmA = (t & 15) * 4;
    const int nnB = t >> 2, kkB = (t & 3) * 4;
    float acc[4][4] = {};                      // [i=m][j=n]
    for (int k0 = 0; k0 < D_MODEL; k0 += 16) {
        *reinterpret_cast<float4*>(&As[kkA][mmA]) = *reinterpret_cast<const float4*>(
            &x[(size_t)b * D_MODEL * LSEQ + (size_t)(k0 + kkA) * LSEQ + l0 + mmA]);
        const float4 bv = *reinterpret_cast<const float4*>(
            &W[(size_t)(n0 + nnB) * D_MODEL + k0 + kkB]);
        Bs[kkB + 0][nnB] = bv.x; Bs[kkB + 1][nnB] = bv.y;
        Bs[kkB + 2][nnB] = bv.z; Bs[kkB + 3][nnB] = bv.w;
        __syncthreads();
#pragma unroll
        for (int kk = 0; kk < 16; ++kk) {
            float a[4], bb[4];
#pragma unroll
            for (int i = 0; i < 4; ++i) a[i] = As[kk][ty * 4 + i];
#pragma unroll
            for (int j = 0; j < 4; ++j) bb[j] = Bs[kk][tx * 4 + j];
#pragma unroll
            for (int i = 0; i < 4; ++i)
#pragma unroll
                for (int j = 0; j < 4; ++j)
                    acc[i][j] = fmaf(a[i], bb[j], acc[i][j]);
        }
        __syncthreads();
    }
    if (n0 < D_INNER) {
#pragma unroll
        for (int i = 0; i < 4; ++i) {
            float4 v = make_float4(acc[i][0], acc[i][1], acc[i][2], acc[i][3]);
            *reinterpret_cast<float4*>(
                &xin[(size_t)(m0 + ty * 4 + i) * D_INNER + n0 + tx * 4]) = v;
        }
    } else {
#pragma unroll
        for (int j = 0; j < 4; ++j) {
            float4 v = make_float4(silu(acc[0][j]), silu(acc[1][j]),
                                   silu(acc[2][j]), silu(acc[3][j]));
            *reinterpret_cast<float4*>(
                &szT[((size_t)b * D_INNER + (n0 - D_INNER) + tx * 4 + j) * LSEQ + l0 + ty * 4]) = v;
        }
    }
}

// ---------------- conv (causal, 3 taps) + SiLU -> u_row [8192][768] and uT [b][d][l]
__global__ __launch_bounds__(256) void k_conv(const float* __restrict__ xin,
                                              const float* __restrict__ cw,
                                              const float* __restrict__ cb,
                                              float* __restrict__ u_row,
                                              float* __restrict__ uT) {
    __shared__ float xs[34][32];
    __shared__ float us[32][33];
    const int d0 = blockIdx.x * 32;   // 24
    const int l0 = blockIdx.y * 32;   // 32
    const int b  = blockIdx.z;        // 8
    const int t = threadIdx.x;
    const int dd = t & 31, r = t >> 5;
    for (int rr = r; rr < 34; rr += 8) {
        const int l = l0 - 2 + rr;
        xs[rr][dd] = (l >= 0) ? xin[((size_t)b * LSEQ + l) * D_INNER + d0 + dd] : 0.f;
    }
    __syncthreads();
    const float w0 = cw[(d0 + dd) * 3 + 0], w1 = cw[(d0 + dd) * 3 + 1], w2 = cw[(d0 + dd) * 3 + 2];
    const float bv = cb[d0 + dd];
#pragma unroll
    for (int p = 0; p < 4; ++p) {
        const int li = r + p * 8;
        float acc = bv;
        acc = fmaf(xs[li + 0][dd], w0, acc);
        acc = fmaf(xs[li + 1][dd], w1, acc);
        acc = fmaf(xs[li + 2][dd], w2, acc);
        const float uv = silu(acc);
        u_row[((size_t)b * LSEQ + l0 + li) * D_INNER + d0 + dd] = uv;
        us[li][dd] = uv;
    }
    __syncthreads();
    const int ll = t & 31, dg = t >> 5;
#pragma unroll
    for (int p = 0; p < 4; ++p) {
        const int dl = dg + p * 8;
        uT[((size_t)b * D_INNER + d0 + dl) * LSEQ + l0 + ll] = us[ll][dl];
    }
}

// ---------------- x_proj: dt cols (0..23) -> dbc row-major; B/C -> bct[b][j][l] transposed
__global__ __launch_bounds__(256) void k_xproj(const float* __restrict__ u,
                                               const float* __restrict__ W,
                                               float* __restrict__ dbc,
                                               float* __restrict__ bct) {
    __shared__ float us[4][D_INNER];
    const int w = threadIdx.x >> 6;
    const int lane = threadIdx.x & 63;
    const int row = blockIdx.x * 4 + w;
#pragma unroll
    for (int it = 0; it < 3; ++it) {
        const int k = it * 256 + lane * 4;
        *reinterpret_cast<float4*>(&us[w][k]) =
            *reinterpret_cast<const float4*>(&u[(size_t)row * D_INNER + k]);
    }
    __syncthreads();
    if (lane < DBC_N) {
        float acc = 0.f;
        for (int k = 0; k < D_INNER; k += 4) {
            const float4 wv = *reinterpret_cast<const float4*>(&W[(size_t)lane * D_INNER + k]);
            acc = fmaf(us[w][k + 0], wv.x, acc);
            acc = fmaf(us[w][k + 1], wv.y, acc);
            acc = fmaf(us[w][k + 2], wv.z, acc);
            acc = fmaf(us[w][k + 3], wv.w, acc);
        }
        if (lane < DT_RANK) {
            dbc[(size_t)row * DBC_N + lane] = acc;
        } else {
            const int b = row >> 10, l = row & 1023;
            bct[((size_t)b * 32 + (lane - DT_RANK)) * LSEQ + l] = acc;
        }
    }
}

// ---------------- dt_proj (K=24) + softplus -> dtT[b][d][l] (transposed via LDS tile)
__global__ __launch_bounds__(256) void k_dtproj(const float* __restrict__ dbc,
                                                const float* __restrict__ W,
                                                const float* __restrict__ bias,
                                                float* __restrict__ dtT) {
    __shared__ float sd[64][25];
    __shared__ float sw[64][24];
    __shared__ float sb[64];
    const int d0 = blockIdx.x * 64;       // 12
    const int row0 = blockIdx.y * 64;     // 128
    const int b = row0 >> 10, lr0 = row0 & 1023;
    const int t = threadIdx.x;
    for (int e = t; e < 64 * 24; e += 256) {
        const int rl = e / 24, rr = e - rl * 24;
        sd[rl][rr] = dbc[(size_t)(row0 + rl) * DBC_N + rr];
        sw[rl][rr] = W[(size_t)(d0 + rl) * DT_RANK + rr];
    }
    if (t < 64) sb[t] = bias[d0 + t];
    __syncthreads();
    const int ll = t & 63, dg = t >> 6;
    for (int dd = 0; dd < 16; ++dd) {
        const int dl = dg * 16 + dd;
        float acc = sb[dl];
#pragma unroll
        for (int r = 0; r < DT_RANK; ++r) acc = fmaf(sd[ll][r], sw[dl][r], acc);
        const float v = (acc > 20.f) ? acc : log1pf(__expf(acc));
        dtT[((size_t)b * D_INNER + d0 + dl) * LSEQ + lr0 + ll] = v;
    }
}

// ---------------- block-parallel selective scan. Block = (d, b); thread = (n, seg).
// Pass A: per-segment (P,H) with h_in=0, P = exp(A*sum(dt)).
// Hillis-Steele inclusive scan over 64 segments (combine: P=Pl*Pc, H=Hl*Pc+Hc).
// Pass C: re-run segment from exact prefix state, reduce over n, fuse +u*D and *silu(z).
// y overwrites dtT in place (block reads its dt slice to LDS first), so no __restrict__.
__global__ __launch_bounds__(1024) void k_scan(float* dtyT,
                                               const float* __restrict__ uT,
                                               const float* __restrict__ szT,
                                               const float* __restrict__ bct,
                                               const float* __restrict__ A_log,
                                               const float* __restrict__ Dp) {
    __shared__ float dt_s[LSEQ], u_s[LSEQ], sz_s[LSEQ], y_s[LSEQ];
    __shared__ float Pb[2][16][NSEG + 1], Hb[2][16][NSEG + 1];
    const int t = threadIdx.x;
    const int d = blockIdx.x;
    const int b = blockIdx.y;
    const size_t base = ((size_t)b * D_INNER + d) * LSEQ;
    if (t < 256) {
        *reinterpret_cast<float4*>(&dt_s[t * 4]) =
            *reinterpret_cast<const float4*>(&dtyT[base + t * 4]);
    } else if (t < 512) {
        const int q = (t - 256) * 4;
        *reinterpret_cast<float4*>(&u_s[q]) = *reinterpret_cast<const float4*>(&uT[base + q]);
    } else if (t < 768) {
        const int q = (t - 512) * 4;
        *reinterpret_cast<float4*>(&sz_s[q]) = *reinterpret_cast<const float4*>(&szT[base + q]);
    }
    const int n = t & 15, seg = t >> 4;
    const float Aval = -__expf(A_log[d * D_STATE + n]);
    const float Dv = Dp[d];
    float Breg[SEG], Creg[SEG];
    {
        const size_t bb = ((size_t)b * 32 + n) * LSEQ + seg * SEG;
        const size_t cc = ((size_t)b * 32 + 16 + n) * LSEQ + seg * SEG;
#pragma unroll
        for (int q = 0; q < SEG; q += 4)
            *reinterpret_cast<float4*>(&Breg[q]) = *reinterpret_cast<const float4*>(&bct[bb + q]);
#pragma unroll
        for (int q = 0; q < SEG; q += 4)
            *reinterpret_cast<float4*>(&Creg[q]) = *reinterpret_cast<const float4*>(&bct[cc + q]);
    }
    __syncthreads();
    const int l0 = seg * SEG;
    // pass A
    float h = 0.f, sdt = 0.f;
#pragma unroll
    for (int l = 0; l < SEG; ++l) {
        const float dtv = dt_s[l0 + l];
        const float a = __expf(dtv * Aval);
        h = fmaf(a, h, dtv * u_s[l0 + l] * Breg[l]);
        sdt += dtv;
    }
    Pb[0][n][seg] = __expf(Aval * sdt);
    Hb[0][n][seg] = h;
    __syncthreads();
    // inclusive scan over segments
    int cur = 0;
#pragma unroll
    for (int off = 1; off < NSEG; off <<= 1) {
        float Pc = Pb[cur][n][seg], Hc = Hb[cur][n][seg];
        if (seg >= off) {
            const float Pl = Pb[cur][n][seg - off], Hl = Hb[cur][n][seg - off];
            Hc = fmaf(Hl, Pc, Hc);
            Pc = Pl * Pc;
        }
        Pb[cur ^ 1][n][seg] = Pc;
        Hb[cur ^ 1][n][seg] = Hc;
        cur ^= 1;
        __syncthreads();
    }
    // pass C
    h = (seg == 0) ? 0.f : Hb[cur][n][seg - 1];
#pragma unroll
    for (int l = 0; l < SEG; ++l) {
        const float dtv = dt_s[l0 + l];
        const float u_v = u_s[l0 + l];
        const float a = __expf(dtv * Aval);
        h = fmaf(a, h, dtv * u_v * Breg[l]);
        float p = h * Creg[l];
        p += __shfl_xor(p, 1);
        p += __shfl_xor(p, 2);
        p += __shfl_xor(p, 4);
        p += __shfl_xor(p, 8);
        if (n == 0)
            y_s[l0 + l] = fmaf(u_v, Dv, p) * sz_s[l0 + l];
    }
    __syncthreads();
    if (t < 256)
        *reinterpret_cast<float4*>(&dtyT[base + t * 4]) =
            *reinterpret_cast<const float4*>(&y_s[t * 4]);
}

// ---------------- GEMM3: out[b][c][l] = sum_d yT[b][d][l] * W[c][d]; A is K-major like inproj.
__global__ __launch_bounds__(256) void k_outproj(const float* __restrict__ yT,
                                                 const float* __restrict__ W,
                                                 float* __restrict__ out) {
    __shared__ float As[16][64];
    __shared__ float Bs[16][64];
    const int n0 = blockIdx.x * 64;   // c-tile: 6
    const int m0 = blockIdx.y * 64;   // row-tile: 128
    const int b = m0 >> 10, l0 = m0 & 1023;
    const int t = threadIdx.x;
    const int tx = t & 15, ty = t >> 4;
    const int kkA = t >> 4, mmA = (t & 15) * 4;
    const int nnB = t >> 2, kkB = (t & 3) * 4;
    float acc[4][4] = {};                      // [i=m][j=n]
    for (int k0 = 0; k0 < D_INNER; k0 += 16) {
        *reinterpret_cast<float4*>(&As[kkA][mmA]) = *reinterpret_cast<const float4*>(
            &yT[((size_t)b * D_INNER + k0 + kkA) * LSEQ + l0 + mmA]);
        const float4 bv = *reinterpret_cast<const float4*>(
            &W[(size_t)(n0 + nnB) * D_INNER + k0 + kkB]);
        Bs[kkB + 0][nnB] = bv.x; Bs[kkB + 1][nnB] = bv.y;
        Bs[kkB + 2][nnB] = bv.z; Bs[kkB + 3][nnB] = bv.w;
        __syncthreads();
#pragma unroll
        for (int kk = 0; kk < 16; ++kk) {
            float a[4], bb[4];
#pragma unroll
            for (int i = 0; i < 4; ++i) a[i] = As[kk][ty * 4 + i];
#pragma unroll
            for (int j = 0; j < 4; ++j) bb[j] = Bs[kk][tx * 4 + j];
#pragma unroll
            for (int i = 0; i < 4; ++i)
#pragma unroll
                for (int j = 0; j < 4; ++j)
                    acc[i][j] = fmaf(a[i], bb[j], acc[i][j]);
        }
        __syncthreads();
    }
#pragma unroll
    for (int j = 0; j < 4; ++j) {
        float4 v = make_float4(acc[0][j], acc[1][j], acc[2][j], acc[3][j]);
        *reinterpret_cast<float4*>(
            &out[(size_t)b * D_MODEL * LSEQ + (size_t)(n0 + tx * 4 + j) * LSEQ + l0 + ty * 4]) = v;
    }
}

extern "C" void kernel_launch(void* const* d_in, const int* in_sizes, int n_in,
                              void* d_out, int out_size, void* d_ws, size_t ws_size,
                              hipStream_t stream) {
    const float* x         = (const float*)d_in[0];
    const float* in_proj_w = (const float*)d_in[1];
    const float* conv_w    = (const float*)d_in[2];
    const float* conv_b    = (const float*)d_in[3];
    const float* x_proj_w  = (const float*)d_in[4];
    const float* dt_proj_w = (const float*)d_in[5];
    const float* dt_proj_b = (const float*)d_in[6];
    const float* A_log     = (const float*)d_in[7];
    const float* Dp        = (const float*)d_in[8];
    const float* out_proj_w= (const float*)d_in[9];
    float* out = (float*)d_out;

    float* ws    = (float*)d_ws;
    float* xin   = ws;                                   // 8192*768
    float* szT   = xin  + (size_t)NROWS * D_INNER;       // 8*768*1024
    float* u_row = szT  + (size_t)NROWS * D_INNER;       // 8192*768 (later: dtT, then yT)
    float* uT    = u_row + (size_t)NROWS * D_INNER;      // 8*768*1024
    float* dbc   = uT   + (size_t)NROWS * D_INNER;       // 8192*56
    float* bct   = dbc  + (size_t)NROWS * DBC_N;         // 8*32*1024
    float* dtyT  = u_row;                                // alias: u_row dead after x_proj

    k_inproj<<<dim3(24, NROWS / 64), 256, 0, stream>>>(x, in_proj_w, xin, szT);
    k_conv<<<dim3(24, 32, NB), 256, 0, stream>>>(xin, conv_w, conv_b, u_row, uT);
    k_xproj<<<NROWS / 4, 256, 0, stream>>>(u_row, x_proj_w, dbc, bct);
    k_dtproj<<<dim3(12, NROWS / 64), 256, 0, stream>>>(dbc, dt_proj_w, dt_proj_b, dtyT);
    k_scan<<<dim3(D_INNER, NB), 1024, 0, stream>>>(dtyT, uT, szT, bct, A_log, Dp);
    k_outproj<<<dim3(6, NROWS / 64), 256, 0, stream>>>(dtyT, out_proj_w, out);
}

// Round 4
// 487.416 us; speedup vs baseline: 2.4198x; 1.1739x over previous
//
#include <hip/hip_runtime.h>

#define D_MODEL 384
#define D_STATE 16
#define D_INNER 768
#define DT_RANK 24
#define NB 8
#define LSEQ 1024
#define NROWS (NB * LSEQ)             // 8192
#define DBC_N 56
#define SEG 16
#define NSEG 64

typedef unsigned short u16;
typedef __attribute__((ext_vector_type(8))) short bf16x8;
typedef __attribute__((ext_vector_type(4))) float f32x4;

__device__ __forceinline__ float silu(float x) { return x / (1.f + __expf(-x)); }

__device__ __forceinline__ u16 f2bf_rne(float v, float& hval) {
    unsigned u = __builtin_bit_cast(unsigned, v);
    unsigned h = (u + 0x7FFFu + ((u >> 16) & 1u)) >> 16;
    hval = __builtin_bit_cast(float, h << 16);
    return (u16)h;
}

// ---------------- weight split: f32 -> bf16 hi/lo
__global__ __launch_bounds__(256) void k_splitw(const float* __restrict__ src,
                                                u16* __restrict__ hi, u16* __restrict__ lo,
                                                int count) {
    const int i = blockIdx.x * 256 + threadIdx.x;
    if (i >= count) return;
    const float v = src[i];
    float hval;
    const u16 h = f2bf_rne(v, hval);
    float dummy;
    const u16 l = f2bf_rne(v - hval, dummy);
    hi[i] = h; lo[i] = l;
}

// ---------------- activation split + transpose: src [B][R][1024] f32 -> hi/lo [B*1024][R] bf16
__global__ __launch_bounds__(256) void k_splitT(const float* __restrict__ src,
                                                u16* __restrict__ hi, u16* __restrict__ lo,
                                                int R) {
    __shared__ float s[32][33];
    const int r0 = blockIdx.x * 32, c0 = blockIdx.y * 32, b = blockIdx.z;
    const int t = threadIdx.x;
    const int cc = t & 31, rr = t >> 5;
#pragma unroll
    for (int p = 0; p < 4; ++p)
        s[rr + p * 8][cc] = src[((size_t)b * R + r0 + rr + p * 8) * LSEQ + c0 + cc];
    __syncthreads();
    const int rr2 = t & 31, cc2 = t >> 5;
#pragma unroll
    for (int p = 0; p < 4; ++p) {
        const int c = cc2 + p * 8;
        const float v = s[rr2][c];
        float hval;
        const u16 h = f2bf_rne(v, hval);
        float dummy;
        const u16 l = f2bf_rne(v - hval, dummy);
        const size_t idx = ((size_t)b * LSEQ + c0 + c) * R + r0 + rr2;
        hi[idx] = h; lo[idx] = l;
    }
}

// ---------------- split-bf16 MFMA GEMM: C[m][n] = sum over 3 segments
// (Ahi*Bhi + Ahi*Blo + Alo*Bhi), A [M][K] bf16 row-major, B [N][K] bf16 (B^T).
// 128x128 tile, BK=32, 4 waves (2x2), double-buffered LDS, reg-staged prefetch.
// MODE 0: in_proj epilogue (xin row-major for n<768, silu->szT transposed for n>=768)
// MODE 1: out_proj epilogue (out[b][n][l] transposed, float4 along l)
template <int K, int MODE>
__global__ __launch_bounds__(256) void k_gemm(const u16* __restrict__ Ahi,
                                              const u16* __restrict__ Alo,
                                              const u16* __restrict__ Bhi,
                                              const u16* __restrict__ Blo,
                                              float* __restrict__ out0,
                                              float* __restrict__ out1) {
    constexpr int KT = K / 32;
    constexpr int NT = 3 * KT;
    __shared__ u16 lA[2][512 * 8];
    __shared__ u16 lB[2][512 * 8];
    const int tid = threadIdx.x;
    const int n0 = blockIdx.x * 128;
    const int m0 = blockIdx.y * 128;

    bf16x8 ra[2], rb[2];
    auto load_tile = [&](int t) {
        const int s = t / KT;
        const int ko = (t - s * KT) * 32;
        const u16* Ab = (s < 2) ? Ahi : Alo;
        const u16* Bb = (s == 1) ? Blo : Bhi;
#pragma unroll
        for (int i = 0; i < 2; ++i) {
            const int slot = tid + 256 * i;
            ra[i] = *reinterpret_cast<const bf16x8*>(
                Ab + (size_t)(m0 + (slot & 127)) * K + ko + (slot >> 7) * 8);
            rb[i] = *reinterpret_cast<const bf16x8*>(
                Bb + (size_t)(n0 + (slot & 127)) * K + ko + (slot >> 7) * 8);
        }
    };
    auto write_tile = [&](int buf) {
#pragma unroll
        for (int i = 0; i < 2; ++i) {
            const int slot = tid + 256 * i;
            *reinterpret_cast<bf16x8*>(&lA[buf][slot * 8]) = ra[i];
            *reinterpret_cast<bf16x8*>(&lB[buf][slot * 8]) = rb[i];
        }
    };

    load_tile(0);
    write_tile(0);
    load_tile(1);

    const int lane = tid & 63, w = tid >> 6;
    const int wm = w >> 1, wn = w & 1;
    const int fr = lane & 15, g = lane >> 4;
    const int abase = (g * 128 + wm * 64 + fr) * 8;
    const int bbase = (g * 128 + wn * 64 + fr) * 8;

    f32x4 acc[4][4] = {};
    for (int t = 0; t < NT; ++t) {
        const int cur = t & 1;
        __syncthreads();
        bf16x8 a[4], b[4];
#pragma unroll
        for (int mi = 0; mi < 4; ++mi)
            a[mi] = *reinterpret_cast<const bf16x8*>(&lA[cur][abase + mi * 128]);
#pragma unroll
        for (int ni = 0; ni < 4; ++ni)
            b[ni] = *reinterpret_cast<const bf16x8*>(&lB[cur][bbase + ni * 128]);
#pragma unroll
        for (int mi = 0; mi < 4; ++mi)
#pragma unroll
            for (int ni = 0; ni < 4; ++ni)
                acc[mi][ni] = __builtin_amdgcn_mfma_f32_16x16x32_bf16(
                    a[mi], b[ni], acc[mi][ni], 0, 0, 0);
        if (t + 1 < NT) {
            __syncthreads();
            write_tile(cur ^ 1);
            if (t + 2 < NT) load_tile(t + 2);
        }
    }

    const int b_idx = m0 >> 10;
    const int l0b = m0 & 1023;
    if (MODE == 0) {
        if (n0 < D_INNER) {
#pragma unroll
            for (int mi = 0; mi < 4; ++mi) {
#pragma unroll
                for (int ni = 0; ni < 4; ++ni) {
                    const int m = m0 + wm * 64 + mi * 16 + (lane >> 4) * 4;
                    const int n = n0 + wn * 64 + ni * 16 + (lane & 15);
#pragma unroll
                    for (int j = 0; j < 4; ++j)
                        out0[(size_t)(m + j) * D_INNER + n] = acc[mi][ni][j];
                }
            }
        } else {
#pragma unroll
            for (int mi = 0; mi < 4; ++mi) {
#pragma unroll
                for (int ni = 0; ni < 4; ++ni) {
                    const int l = l0b + wm * 64 + mi * 16 + (lane >> 4) * 4;
                    const int d = (n0 - D_INNER) + wn * 64 + ni * 16 + (lane & 15);
                    float4 v = make_float4(silu(acc[mi][ni][0]), silu(acc[mi][ni][1]),
                                           silu(acc[mi][ni][2]), silu(acc[mi][ni][3]));
                    *reinterpret_cast<float4*>(
                        &out1[((size_t)b_idx * D_INNER + d) * LSEQ + l]) = v;
                }
            }
        }
    } else {
#pragma unroll
        for (int mi = 0; mi < 4; ++mi) {
#pragma unroll
            for (int ni = 0; ni < 4; ++ni) {
                const int l = l0b + wm * 64 + mi * 16 + (lane >> 4) * 4;
                const int n = n0 + wn * 64 + ni * 16 + (lane & 15);
                float4 v = make_float4(acc[mi][ni][0], acc[mi][ni][1],
                                       acc[mi][ni][2], acc[mi][ni][3]);
                *reinterpret_cast<float4*>(
                    &out0[((size_t)b_idx * D_MODEL + n) * LSEQ + l]) = v;
            }
        }
    }
}

// ---------------- conv (causal, 3 taps) + SiLU -> u_row [8192][768] and uT [b][d][l]
__global__ __launch_bounds__(256) void k_conv(const float* __restrict__ xin,
                                              const float* __restrict__ cw,
                                              const float* __restrict__ cb,
                                              float* __restrict__ u_row,
                                              float* __restrict__ uT) {
    __shared__ float xs[34][32];
    __shared__ float us[32][33];
    const int d0 = blockIdx.x * 32;
    const int l0 = blockIdx.y * 32;
    const int b  = blockIdx.z;
    const int t = threadIdx.x;
    const int dd = t & 31, r = t >> 5;
    for (int rr = r; rr < 34; rr += 8) {
        const int l = l0 - 2 + rr;
        xs[rr][dd] = (l >= 0) ? xin[((size_t)b * LSEQ + l) * D_INNER + d0 + dd] : 0.f;
    }
    __syncthreads();
    const float w0 = cw[(d0 + dd) * 3 + 0], w1 = cw[(d0 + dd) * 3 + 1], w2 = cw[(d0 + dd) * 3 + 2];
    const float bv = cb[d0 + dd];
#pragma unroll
    for (int p = 0; p < 4; ++p) {
        const int li = r + p * 8;
        float acc = bv;
        acc = fmaf(xs[li + 0][dd], w0, acc);
        acc = fmaf(xs[li + 1][dd], w1, acc);
        acc = fmaf(xs[li + 2][dd], w2, acc);
        const float uv = silu(acc);
        u_row[((size_t)b * LSEQ + l0 + li) * D_INNER + d0 + dd] = uv;
        us[li][dd] = uv;
    }
    __syncthreads();
    const int ll = t & 31, dg = t >> 5;
#pragma unroll
    for (int p = 0; p < 4; ++p) {
        const int dl = dg + p * 8;
        uT[((size_t)b * D_INNER + d0 + dl) * LSEQ + l0 + ll] = us[ll][dl];
    }
}

// ---------------- x_proj: dt cols (0..23) -> dbc row-major; B/C -> bct[b][j][l] transposed
__global__ __launch_bounds__(256) void k_xproj(const float* __restrict__ u,
                                               const float* __restrict__ W,
                                               float* __restrict__ dbc,
                                               float* __restrict__ bct) {
    __shared__ float us[4][D_INNER];
    const int w = threadIdx.x >> 6;
    const int lane = threadIdx.x & 63;
    const int row = blockIdx.x * 4 + w;
#pragma unroll
    for (int it = 0; it < 3; ++it) {
        const int k = it * 256 + lane * 4;
        *reinterpret_cast<float4*>(&us[w][k]) =
            *reinterpret_cast<const float4*>(&u[(size_t)row * D_INNER + k]);
    }
    __syncthreads();
    if (lane < DBC_N) {
        float acc = 0.f;
        for (int k = 0; k < D_INNER; k += 4) {
            const float4 wv = *reinterpret_cast<const float4*>(&W[(size_t)lane * D_INNER + k]);
            acc = fmaf(us[w][k + 0], wv.x, acc);
            acc = fmaf(us[w][k + 1], wv.y, acc);
            acc = fmaf(us[w][k + 2], wv.z, acc);
            acc = fmaf(us[w][k + 3], wv.w, acc);
        }
        if (lane < DT_RANK) {
            dbc[(size_t)row * DBC_N + lane] = acc;
        } else {
            const int b = row >> 10, l = row & 1023;
            bct[((size_t)b * 32 + (lane - DT_RANK)) * LSEQ + l] = acc;
        }
    }
}

// ---------------- dt_proj (K=24) + softplus -> dtT[b][d][l] (transposed via LDS tile)
__global__ __launch_bounds__(256) void k_dtproj(const float* __restrict__ dbc,
                                                const float* __restrict__ W,
                                                const float* __restrict__ bias,
                                                float* __restrict__ dtT) {
    __shared__ float sd[64][25];
    __shared__ float sw[64][24];
    __shared__ float sb[64];
    const int d0 = blockIdx.x * 64;
    const int row0 = blockIdx.y * 64;
    const int b = row0 >> 10, lr0 = row0 & 1023;
    const int t = threadIdx.x;
    for (int e = t; e < 64 * 24; e += 256) {
        const int rl = e / 24, rr = e - rl * 24;
        sd[rl][rr] = dbc[(size_t)(row0 + rl) * DBC_N + rr];
        sw[rl][rr] = W[(size_t)(d0 + rl) * DT_RANK + rr];
    }
    if (t < 64) sb[t] = bias[d0 + t];
    __syncthreads();
    const int ll = t & 63, dg = t >> 6;
    for (int dd = 0; dd < 16; ++dd) {
        const int dl = dg * 16 + dd;
        float acc = sb[dl];
#pragma unroll
        for (int r = 0; r < DT_RANK; ++r) acc = fmaf(sd[ll][r], sw[dl][r], acc);
        const float v = (acc > 20.f) ? acc : log1pf(__expf(acc));
        dtT[((size_t)b * D_INNER + d0 + dl) * LSEQ + lr0 + ll] = v;
    }
}

// ---------------- block-parallel selective scan (unchanged from R2)
__global__ __launch_bounds__(1024) void k_scan(float* dtyT,
                                               const float* __restrict__ uT,
                                               const float* __restrict__ szT,
                                               const float* __restrict__ bct,
                                               const float* __restrict__ A_log,
                                               const float* __restrict__ Dp) {
    __shared__ float dt_s[LSEQ], u_s[LSEQ], sz_s[LSEQ], y_s[LSEQ];
    __shared__ float Pb[2][16][NSEG + 1], Hb[2][16][NSEG + 1];
    const int t = threadIdx.x;
    const int d = blockIdx.x;
    const int b = blockIdx.y;
    const size_t base = ((size_t)b * D_INNER + d) * LSEQ;
    if (t < 256) {
        *reinterpret_cast<float4*>(&dt_s[t * 4]) =
            *reinterpret_cast<const float4*>(&dtyT[base + t * 4]);
    } else if (t < 512) {
        const int q = (t - 256) * 4;
        *reinterpret_cast<float4*>(&u_s[q]) = *reinterpret_cast<const float4*>(&uT[base + q]);
    } else if (t < 768) {
        const int q = (t - 512) * 4;
        *reinterpret_cast<float4*>(&sz_s[q]) = *reinterpret_cast<const float4*>(&szT[base + q]);
    }
    const int n = t & 15, seg = t >> 4;
    const float Aval = -__expf(A_log[d * D_STATE + n]);
    const float Dv = Dp[d];
    float Breg[SEG], Creg[SEG];
    {
        const size_t bb = ((size_t)b * 32 + n) * LSEQ + seg * SEG;
        const size_t cc = ((size_t)b * 32 + 16 + n) * LSEQ + seg * SEG;
#pragma unroll
        for (int q = 0; q < SEG; q += 4)
            *reinterpret_cast<float4*>(&Breg[q]) = *reinterpret_cast<const float4*>(&bct[bb + q]);
#pragma unroll
        for (int q = 0; q < SEG; q += 4)
            *reinterpret_cast<float4*>(&Creg[q]) = *reinterpret_cast<const float4*>(&bct[cc + q]);
    }
    __syncthreads();
    const int l0 = seg * SEG;
    float h = 0.f, sdt = 0.f;
#pragma unroll
    for (int l = 0; l < SEG; ++l) {
        const float dtv = dt_s[l0 + l];
        const float a = __expf(dtv * Aval);
        h = fmaf(a, h, dtv * u_s[l0 + l] * Breg[l]);
        sdt += dtv;
    }
    Pb[0][n][seg] = __expf(Aval * sdt);
    Hb[0][n][seg] = h;
    __syncthreads();
    int cur = 0;
#pragma unroll
    for (int off = 1; off < NSEG; off <<= 1) {
        float Pc = Pb[cur][n][seg], Hc = Hb[cur][n][seg];
        if (seg >= off) {
            const float Pl = Pb[cur][n][seg - off], Hl = Hb[cur][n][seg - off];
            Hc = fmaf(Hl, Pc, Hc);
            Pc = Pl * Pc;
        }
        Pb[cur ^ 1][n][seg] = Pc;
        Hb[cur ^ 1][n][seg] = Hc;
        cur ^= 1;
        __syncthreads();
    }
    h = (seg == 0) ? 0.f : Hb[cur][n][seg - 1];
#pragma unroll
    for (int l = 0; l < SEG; ++l) {
        const float dtv = dt_s[l0 + l];
        const float u_v = u_s[l0 + l];
        const float a = __expf(dtv * Aval);
        h = fmaf(a, h, dtv * u_v * Breg[l]);
        float p = h * Creg[l];
        p += __shfl_xor(p, 1);
        p += __shfl_xor(p, 2);
        p += __shfl_xor(p, 4);
        p += __shfl_xor(p, 8);
        if (n == 0)
            y_s[l0 + l] = fmaf(u_v, Dv, p) * sz_s[l0 + l];
    }
    __syncthreads();
    if (t < 256)
        *reinterpret_cast<float4*>(&dtyT[base + t * 4]) =
            *reinterpret_cast<const float4*>(&y_s[t * 4]);
}

extern "C" void kernel_launch(void* const* d_in, const int* in_sizes, int n_in,
                              void* d_out, int out_size, void* d_ws, size_t ws_size,
                              hipStream_t stream) {
    const float* x         = (const float*)d_in[0];
    const float* in_proj_w = (const float*)d_in[1];
    const float* conv_w    = (const float*)d_in[2];
    const float* conv_b    = (const float*)d_in[3];
    const float* x_proj_w  = (const float*)d_in[4];
    const float* dt_proj_w = (const float*)d_in[5];
    const float* dt_proj_b = (const float*)d_in[6];
    const float* A_log     = (const float*)d_in[7];
    const float* Dp        = (const float*)d_in[8];
    const float* out_proj_w= (const float*)d_in[9];
    float* out = (float*)d_out;

    const size_t SB = (size_t)NROWS * D_INNER * 4;   // 25.2 MB
    char* wsb = (char*)d_ws;
    float* xin   = (float*)(wsb);
    float* szT   = (float*)(wsb + SB);
    float* u_row = (float*)(wsb + 2 * SB);
    float* uT    = (float*)(wsb + 3 * SB);
    float* dbc   = (float*)(wsb + 4 * SB);
    float* bct   = (float*)(wsb + 4 * SB + 1835008);
    u16*  Wi_hi  = (u16*) (wsb + 4 * SB + 1835008 + 1048576);
    u16*  Wi_lo  = Wi_hi + 1536 * 384;
    u16*  Wo_hi  = Wi_lo + 1536 * 384;
    u16*  Wo_lo  = Wo_hi + 384 * 768;
    u16*  Ax_hi  = (u16*)uT;                 // dead before conv writes uT
    u16*  Ax_lo  = Ax_hi + (size_t)NROWS * 384;
    u16*  Ay_hi  = (u16*)xin;                // xin dead after conv
    u16*  Ay_lo  = Ay_hi + (size_t)NROWS * 768;
    float* dtyT  = u_row;                    // dt, then y in place

    k_splitw<<<(1536 * 384 + 255) / 256, 256, 0, stream>>>(in_proj_w, Wi_hi, Wi_lo, 1536 * 384);
    k_splitw<<<(384 * 768 + 255) / 256, 256, 0, stream>>>(out_proj_w, Wo_hi, Wo_lo, 384 * 768);
    k_splitT<<<dim3(12, 32, NB), 256, 0, stream>>>(x, Ax_hi, Ax_lo, 384);
    k_gemm<384, 0><<<dim3(12, 64), 256, 0, stream>>>(Ax_hi, Ax_lo, Wi_hi, Wi_lo, xin, szT);
    k_conv<<<dim3(24, 32, NB), 256, 0, stream>>>(xin, conv_w, conv_b, u_row, uT);
    k_xproj<<<NROWS / 4, 256, 0, stream>>>(u_row, x_proj_w, dbc, bct);
    k_dtproj<<<dim3(12, NROWS / 64), 256, 0, stream>>>(dbc, dt_proj_w, dt_proj_b, dtyT);
    k_scan<<<dim3(D_INNER, NB), 1024, 0, stream>>>(dtyT, uT, szT, bct, A_log, Dp);
    k_splitT<<<dim3(24, 32, NB), 256, 0, stream>>>(dtyT, Ay_hi, Ay_lo, 768);
    k_gemm<768, 1><<<dim3(3, 64), 256, 0, stream>>>(Ay_hi, Ay_lo, Wo_hi, Wo_lo, out, nullptr);
}

// Round 5
// 357.935 us; speedup vs baseline: 3.2952x; 1.3617x over previous
//
#include <hip/hip_runtime.h>

#define D_MODEL 384
#define D_STATE 16
#define D_INNER 768
#define DT_RANK 24
#define NB 8
#define LSEQ 1024
#define NROWS (NB * LSEQ)             // 8192
#define DBC_N 56
#define SEG 16
#define NSEG 64

typedef unsigned short u16;
typedef __attribute__((ext_vector_type(8))) short bf16x8;
typedef __attribute__((ext_vector_type(4))) float f32x4;

__device__ __forceinline__ float silu(float x) { return x / (1.f + __expf(-x)); }

__device__ __forceinline__ u16 f2bf_rne(float v, float& hval) {
    unsigned u = __builtin_bit_cast(unsigned, v);
    unsigned h = (u + 0x7FFFu + ((u >> 16) & 1u)) >> 16;
    hval = __builtin_bit_cast(float, h << 16);
    return (u16)h;
}

__device__ __forceinline__ void split2(float v, u16& h, u16& l) {
    float hval, dummy;
    h = f2bf_rne(v, hval);
    l = f2bf_rne(v - hval, dummy);
}

// ---------------- weight split: f32 -> bf16 hi/lo
__global__ __launch_bounds__(256) void k_splitw(const float* __restrict__ src,
                                                u16* __restrict__ hi, u16* __restrict__ lo,
                                                int count) {
    const int i = blockIdx.x * 256 + threadIdx.x;
    if (i >= count) return;
    u16 h, l;
    split2(src[i], h, l);
    hi[i] = h; lo[i] = l;
}

// ---------------- x_proj weight split, padded 56 -> 64 rows (zeros)
__global__ __launch_bounds__(256) void k_splitw_pad(const float* __restrict__ src,
                                                    u16* __restrict__ hi, u16* __restrict__ lo) {
    const int i = blockIdx.x * 256 + threadIdx.x;   // over 64*768
    if (i >= 64 * 768) return;
    const int row = i / 768;
    u16 h = 0, l = 0;
    if (row < DBC_N) split2(src[i], h, l);
    hi[i] = h; lo[i] = l;
}

// ---------------- activation split + transpose: src [B][R][1024] f32 -> hi/lo [B*1024][R] bf16
__global__ __launch_bounds__(256) void k_splitT(const float* __restrict__ src,
                                                u16* __restrict__ hi, u16* __restrict__ lo,
                                                int R) {
    __shared__ float s[32][33];
    const int r0 = blockIdx.x * 32, c0 = blockIdx.y * 32, b = blockIdx.z;
    const int t = threadIdx.x;
    const int cc = t & 31, rr = t >> 5;
#pragma unroll
    for (int p = 0; p < 4; ++p)
        s[rr + p * 8][cc] = src[((size_t)b * R + r0 + rr + p * 8) * LSEQ + c0 + cc];
    __syncthreads();
    const int rr2 = t & 31, cc2 = t >> 5;
#pragma unroll
    for (int p = 0; p < 4; ++p) {
        const int c = cc2 + p * 8;
        u16 h, l;
        split2(s[rr2][c], h, l);
        const size_t idx = ((size_t)b * LSEQ + c0 + c) * R + r0 + rr2;
        hi[idx] = h; lo[idx] = l;
    }
}

// ---------------- split-bf16 MFMA GEMM (128x128 tile), 3 segments.
// MODE 0: in_proj epilogue; MODE 1: out_proj epilogue
template <int K, int MODE>
__global__ __launch_bounds__(256) void k_gemm(const u16* __restrict__ Ahi,
                                              const u16* __restrict__ Alo,
                                              const u16* __restrict__ Bhi,
                                              const u16* __restrict__ Blo,
                                              float* __restrict__ out0,
                                              float* __restrict__ out1) {
    constexpr int KT = K / 32;
    constexpr int NT = 3 * KT;
    __shared__ u16 lA[2][512 * 8];
    __shared__ u16 lB[2][512 * 8];
    const int tid = threadIdx.x;
    const int n0 = blockIdx.x * 128;
    const int m0 = blockIdx.y * 128;

    bf16x8 ra[2], rb[2];
    auto load_tile = [&](int t) {
        const int s = t / KT;
        const int ko = (t - s * KT) * 32;
        const u16* Ab = (s < 2) ? Ahi : Alo;
        const u16* Bb = (s == 1) ? Blo : Bhi;
#pragma unroll
        for (int i = 0; i < 2; ++i) {
            const int slot = tid + 256 * i;
            ra[i] = *reinterpret_cast<const bf16x8*>(
                Ab + (size_t)(m0 + (slot & 127)) * K + ko + (slot >> 7) * 8);
            rb[i] = *reinterpret_cast<const bf16x8*>(
                Bb + (size_t)(n0 + (slot & 127)) * K + ko + (slot >> 7) * 8);
        }
    };
    auto write_tile = [&](int buf) {
#pragma unroll
        for (int i = 0; i < 2; ++i) {
            const int slot = tid + 256 * i;
            *reinterpret_cast<bf16x8*>(&lA[buf][slot * 8]) = ra[i];
            *reinterpret_cast<bf16x8*>(&lB[buf][slot * 8]) = rb[i];
        }
    };

    load_tile(0);
    write_tile(0);
    load_tile(1);

    const int lane = tid & 63, w = tid >> 6;
    const int wm = w >> 1, wn = w & 1;
    const int fr = lane & 15, g = lane >> 4;
    const int abase = (g * 128 + wm * 64 + fr) * 8;
    const int bbase = (g * 128 + wn * 64 + fr) * 8;

    f32x4 acc[4][4] = {};
    for (int t = 0; t < NT; ++t) {
        const int cur = t & 1;
        __syncthreads();
        bf16x8 a[4], b[4];
#pragma unroll
        for (int mi = 0; mi < 4; ++mi)
            a[mi] = *reinterpret_cast<const bf16x8*>(&lA[cur][abase + mi * 128]);
#pragma unroll
        for (int ni = 0; ni < 4; ++ni)
            b[ni] = *reinterpret_cast<const bf16x8*>(&lB[cur][bbase + ni * 128]);
#pragma unroll
        for (int mi = 0; mi < 4; ++mi)
#pragma unroll
            for (int ni = 0; ni < 4; ++ni)
                acc[mi][ni] = __builtin_amdgcn_mfma_f32_16x16x32_bf16(
                    a[mi], b[ni], acc[mi][ni], 0, 0, 0);
        if (t + 1 < NT) {
            __syncthreads();
            write_tile(cur ^ 1);
            if (t + 2 < NT) load_tile(t + 2);
        }
    }

    const int b_idx = m0 >> 10;
    const int l0b = m0 & 1023;
    if (MODE == 0) {
        if (n0 < D_INNER) {
#pragma unroll
            for (int mi = 0; mi < 4; ++mi) {
#pragma unroll
                for (int ni = 0; ni < 4; ++ni) {
                    const int m = m0 + wm * 64 + mi * 16 + (lane >> 4) * 4;
                    const int n = n0 + wn * 64 + ni * 16 + (lane & 15);
#pragma unroll
                    for (int j = 0; j < 4; ++j)
                        out0[(size_t)(m + j) * D_INNER + n] = acc[mi][ni][j];
                }
            }
        } else {
#pragma unroll
            for (int mi = 0; mi < 4; ++mi) {
#pragma unroll
                for (int ni = 0; ni < 4; ++ni) {
                    const int l = l0b + wm * 64 + mi * 16 + (lane >> 4) * 4;
                    const int d = (n0 - D_INNER) + wn * 64 + ni * 16 + (lane & 15);
                    float4 v = make_float4(silu(acc[mi][ni][0]), silu(acc[mi][ni][1]),
                                           silu(acc[mi][ni][2]), silu(acc[mi][ni][3]));
                    *reinterpret_cast<float4*>(
                        &out1[((size_t)b_idx * D_INNER + d) * LSEQ + l]) = v;
                }
            }
        }
    } else {
#pragma unroll
        for (int mi = 0; mi < 4; ++mi) {
#pragma unroll
            for (int ni = 0; ni < 4; ++ni) {
                const int l = l0b + wm * 64 + mi * 16 + (lane >> 4) * 4;
                const int n = n0 + wn * 64 + ni * 16 + (lane & 15);
                float4 v = make_float4(acc[mi][ni][0], acc[mi][ni][1],
                                       acc[mi][ni][2], acc[mi][ni][3]);
                *reinterpret_cast<float4*>(
                    &out0[((size_t)b_idx * D_MODEL + n) * LSEQ + l]) = v;
            }
        }
    }
}

// ---------------- x_proj MFMA GEMM: M=8192 (64-row tiles), N=64 (padded), K=768, 3 segments.
// Epilogue: n<24 -> dbc row-major; 24<=n<56 -> bct[b][n-24][l]; n>=56 discarded.
__global__ __launch_bounds__(256) void k_xprojm(const u16* __restrict__ Uhi,
                                                const u16* __restrict__ Ulo,
                                                const u16* __restrict__ Whi,
                                                const u16* __restrict__ Wlo,
                                                float* __restrict__ dbc,
                                                float* __restrict__ bct) {
    __shared__ u16 lA[2][64 * 32];
    __shared__ u16 lB[2][64 * 32];
    const int tid = threadIdx.x;
    const int m0 = blockIdx.x * 64;
    const int arow = tid >> 2, acol = (tid & 3) * 8;

    bf16x8 ra, rb;
    auto load_tile = [&](int t) {
        const int s = t / 24;
        const int ko = (t - s * 24) * 32;
        const u16* Ab = (s < 2) ? Uhi : Ulo;
        const u16* Bb = (s == 1) ? Wlo : Whi;
        ra = *reinterpret_cast<const bf16x8*>(Ab + (size_t)(m0 + arow) * D_INNER + ko + acol);
        rb = *reinterpret_cast<const bf16x8*>(Bb + (size_t)arow * D_INNER + ko + acol);
    };
    auto write_tile = [&](int buf) {
        *reinterpret_cast<bf16x8*>(&lA[buf][arow * 32 + acol]) = ra;
        *reinterpret_cast<bf16x8*>(&lB[buf][arow * 32 + acol]) = rb;
    };

    load_tile(0);
    write_tile(0);
    load_tile(1);

    const int lane = tid & 63, w = tid >> 6;
    const int fr = lane & 15, g = lane >> 4;
    f32x4 acc[4] = {};
    for (int t = 0; t < 72; ++t) {
        const int cur = t & 1;
        __syncthreads();
        bf16x8 a = *reinterpret_cast<const bf16x8*>(&lA[cur][(w * 16 + fr) * 32 + g * 8]);
        bf16x8 b[4];
#pragma unroll
        for (int ni = 0; ni < 4; ++ni)
            b[ni] = *reinterpret_cast<const bf16x8*>(&lB[cur][(ni * 16 + fr) * 32 + g * 8]);
#pragma unroll
        for (int ni = 0; ni < 4; ++ni)
            acc[ni] = __builtin_amdgcn_mfma_f32_16x16x32_bf16(a, b[ni], acc[ni], 0, 0, 0);
        if (t + 1 < 72) {
            __syncthreads();
            write_tile(cur ^ 1);
            if (t + 2 < 72) load_tile(t + 2);
        }
    }

    const int b_idx = m0 >> 10;
#pragma unroll
    for (int ni = 0; ni < 4; ++ni) {
        const int col = ni * 16 + fr;
#pragma unroll
        for (int j = 0; j < 4; ++j) {
            const int r = w * 16 + g * 4 + j;
            const float v = acc[ni][j];
            if (col < DT_RANK) {
                dbc[(size_t)(m0 + r) * DBC_N + col] = v;
            } else if (col < DBC_N) {
                bct[((size_t)b_idx * 32 + (col - DT_RANK)) * LSEQ + ((m0 & 1023) + r)] = v;
            }
        }
    }
}

// ---------------- conv (causal, 3 taps) + SiLU -> uT [b][d][l] f32 + u split bf16 row-major
__global__ __launch_bounds__(256) void k_conv(const float* __restrict__ xin,
                                              const float* __restrict__ cw,
                                              const float* __restrict__ cb,
                                              u16* __restrict__ u_hi,
                                              u16* __restrict__ u_lo,
                                              float* __restrict__ uT) {
    __shared__ float xs[34][32];
    __shared__ float us[32][33];
    const int d0 = blockIdx.x * 32;
    const int l0 = blockIdx.y * 32;
    const int b  = blockIdx.z;
    const int t = threadIdx.x;
    const int dd = t & 31, r = t >> 5;
    for (int rr = r; rr < 34; rr += 8) {
        const int l = l0 - 2 + rr;
        xs[rr][dd] = (l >= 0) ? xin[((size_t)b * LSEQ + l) * D_INNER + d0 + dd] : 0.f;
    }
    __syncthreads();
    const float w0 = cw[(d0 + dd) * 3 + 0], w1 = cw[(d0 + dd) * 3 + 1], w2 = cw[(d0 + dd) * 3 + 2];
    const float bv = cb[d0 + dd];
#pragma unroll
    for (int p = 0; p < 4; ++p) {
        const int li = r + p * 8;
        float acc = bv;
        acc = fmaf(xs[li + 0][dd], w0, acc);
        acc = fmaf(xs[li + 1][dd], w1, acc);
        acc = fmaf(xs[li + 2][dd], w2, acc);
        const float uv = silu(acc);
        u16 h, l;
        split2(uv, h, l);
        const size_t idx = ((size_t)b * LSEQ + l0 + li) * D_INNER + d0 + dd;
        u_hi[idx] = h; u_lo[idx] = l;
        us[li][dd] = uv;
    }
    __syncthreads();
    const int ll = t & 31, dg = t >> 5;
#pragma unroll
    for (int p = 0; p < 4; ++p) {
        const int dl = dg + p * 8;
        uT[((size_t)b * D_INNER + d0 + dl) * LSEQ + l0 + ll] = us[ll][dl];
    }
}

// ---------------- dt_proj (K=24) + softplus -> dtT[b][d][l] (transposed via LDS tile)
__global__ __launch_bounds__(256) void k_dtproj(const float* __restrict__ dbc,
                                                const float* __restrict__ W,
                                                const float* __restrict__ bias,
                                                float* __restrict__ dtT) {
    __shared__ float sd[64][25];
    __shared__ float sw[64][24];
    __shared__ float sb[64];
    const int d0 = blockIdx.x * 64;
    const int row0 = blockIdx.y * 64;
    const int b = row0 >> 10, lr0 = row0 & 1023;
    const int t = threadIdx.x;
    for (int e = t; e < 64 * 24; e += 256) {
        const int rl = e / 24, rr = e - rl * 24;
        sd[rl][rr] = dbc[(size_t)(row0 + rl) * DBC_N + rr];
        sw[rl][rr] = W[(size_t)(d0 + rl) * DT_RANK + rr];
    }
    if (t < 64) sb[t] = bias[d0 + t];
    __syncthreads();
    const int ll = t & 63, dg = t >> 6;
    for (int dd = 0; dd < 16; ++dd) {
        const int dl = dg * 16 + dd;
        float acc = sb[dl];
#pragma unroll
        for (int r = 0; r < DT_RANK; ++r) acc = fmaf(sd[ll][r], sw[dl][r], acc);
        const float v = (acc > 20.f) ? acc : log1pf(__expf(acc));
        dtT[((size_t)b * D_INNER + d0 + dl) * LSEQ + lr0 + ll] = v;
    }
}

// ---------------- block-parallel selective scan
__global__ __launch_bounds__(1024) void k_scan(float* dtyT,
                                               const float* __restrict__ uT,
                                               const float* __restrict__ szT,
                                               const float* __restrict__ bct,
                                               const float* __restrict__ A_log,
                                               const float* __restrict__ Dp) {
    __shared__ float dt_s[LSEQ], u_s[LSEQ], sz_s[LSEQ], y_s[LSEQ];
    __shared__ float Pb[2][16][NSEG + 1], Hb[2][16][NSEG + 1];
    const int t = threadIdx.x;
    const int d = blockIdx.x;
    const int b = blockIdx.y;
    const size_t base = ((size_t)b * D_INNER + d) * LSEQ;
    if (t < 256) {
        *reinterpret_cast<float4*>(&dt_s[t * 4]) =
            *reinterpret_cast<const float4*>(&dtyT[base + t * 4]);
    } else if (t < 512) {
        const int q = (t - 256) * 4;
        *reinterpret_cast<float4*>(&u_s[q]) = *reinterpret_cast<const float4*>(&uT[base + q]);
    } else if (t < 768) {
        const int q = (t - 512) * 4;
        *reinterpret_cast<float4*>(&sz_s[q]) = *reinterpret_cast<const float4*>(&szT[base + q]);
    }
    const int n = t & 15, seg = t >> 4;
    const float Aval = -__expf(A_log[d * D_STATE + n]);
    const float Dv = Dp[d];
    float Breg[SEG], Creg[SEG];
    {
        const size_t bb = ((size_t)b * 32 + n) * LSEQ + seg * SEG;
        const size_t cc = ((size_t)b * 32 + 16 + n) * LSEQ + seg * SEG;
#pragma unroll
        for (int q = 0; q < SEG; q += 4)
            *reinterpret_cast<float4*>(&Breg[q]) = *reinterpret_cast<const float4*>(&bct[bb + q]);
#pragma unroll
        for (int q = 0; q < SEG; q += 4)
            *reinterpret_cast<float4*>(&Creg[q]) = *reinterpret_cast<const float4*>(&bct[cc + q]);
    }
    __syncthreads();
    const int l0 = seg * SEG;
    float h = 0.f, sdt = 0.f;
#pragma unroll
    for (int l = 0; l < SEG; ++l) {
        const float dtv = dt_s[l0 + l];
        const float a = __expf(dtv * Aval);
        h = fmaf(a, h, dtv * u_s[l0 + l] * Breg[l]);
        sdt += dtv;
    }
    Pb[0][n][seg] = __expf(Aval * sdt);
    Hb[0][n][seg] = h;
    __syncthreads();
    int cur = 0;
#pragma unroll
    for (int off = 1; off < NSEG; off <<= 1) {
        float Pc = Pb[cur][n][seg], Hc = Hb[cur][n][seg];
        if (seg >= off) {
            const float Pl = Pb[cur][n][seg - off], Hl = Hb[cur][n][seg - off];
            Hc = fmaf(Hl, Pc, Hc);
            Pc = Pl * Pc;
        }
        Pb[cur ^ 1][n][seg] = Pc;
        Hb[cur ^ 1][n][seg] = Hc;
        cur ^= 1;
        __syncthreads();
    }
    h = (seg == 0) ? 0.f : Hb[cur][n][seg - 1];
#pragma unroll
    for (int l = 0; l < SEG; ++l) {
        const float dtv = dt_s[l0 + l];
        const float u_v = u_s[l0 + l];
        const float a = __expf(dtv * Aval);
        h = fmaf(a, h, dtv * u_v * Breg[l]);
        float p = h * Creg[l];
        p += __shfl_xor(p, 1);
        p += __shfl_xor(p, 2);
        p += __shfl_xor(p, 4);
        p += __shfl_xor(p, 8);
        if (n == 0)
            y_s[l0 + l] = fmaf(u_v, Dv, p) * sz_s[l0 + l];
    }
    __syncthreads();
    if (t < 256)
        *reinterpret_cast<float4*>(&dtyT[base + t * 4]) =
            *reinterpret_cast<const float4*>(&y_s[t * 4]);
}

extern "C" void kernel_launch(void* const* d_in, const int* in_sizes, int n_in,
                              void* d_out, int out_size, void* d_ws, size_t ws_size,
                              hipStream_t stream) {
    const float* x         = (const float*)d_in[0];
    const float* in_proj_w = (const float*)d_in[1];
    const float* conv_w    = (const float*)d_in[2];
    const float* conv_b    = (const float*)d_in[3];
    const float* x_proj_w  = (const float*)d_in[4];
    const float* dt_proj_w = (const float*)d_in[5];
    const float* dt_proj_b = (const float*)d_in[6];
    const float* A_log     = (const float*)d_in[7];
    const float* Dp        = (const float*)d_in[8];
    const float* out_proj_w= (const float*)d_in[9];
    float* out = (float*)d_out;

    const size_t SB = (size_t)NROWS * D_INNER * 4;   // 25.2 MB
    char* wsb = (char*)d_ws;
    float* xin   = (float*)(wsb);                    // R0: xin, then dtT/y
    float* szT   = (float*)(wsb + SB);               // R1
    u16*  u_hi   = (u16*)  (wsb + 2 * SB);           // R2: u split bf16
    u16*  u_lo   = u_hi + (size_t)NROWS * D_INNER;
    float* uT    = (float*)(wsb + 3 * SB);           // R3: Ax split, then uT, then Ay split
    float* dbc   = (float*)(wsb + 4 * SB);
    float* bct   = (float*)(wsb + 4 * SB + 1835008);
    u16*  Wi_hi  = (u16*) (wsb + 4 * SB + 1835008 + 1048576);
    u16*  Wi_lo  = Wi_hi + 1536 * 384;
    u16*  Wo_hi  = Wi_lo + 1536 * 384;
    u16*  Wo_lo  = Wo_hi + 384 * 768;
    u16*  Wx_hi  = Wo_lo + 384 * 768;
    u16*  Wx_lo  = Wx_hi + 64 * 768;
    u16*  Ax_hi  = (u16*)uT;                 // dead before conv writes uT
    u16*  Ax_lo  = Ax_hi + (size_t)NROWS * 384;
    u16*  Ay_hi  = (u16*)uT;                 // uT dead after scan
    u16*  Ay_lo  = Ay_hi + (size_t)NROWS * 768;
    float* dtyT  = xin;                      // xin dead after conv; dt then y in place

    k_splitw<<<(1536 * 384 + 255) / 256, 256, 0, stream>>>(in_proj_w, Wi_hi, Wi_lo, 1536 * 384);
    k_splitw<<<(384 * 768 + 255) / 256, 256, 0, stream>>>(out_proj_w, Wo_hi, Wo_lo, 384 * 768);
    k_splitw_pad<<<(64 * 768 + 255) / 256, 256, 0, stream>>>(x_proj_w, Wx_hi, Wx_lo);
    k_splitT<<<dim3(12, 32, NB), 256, 0, stream>>>(x, Ax_hi, Ax_lo, 384);
    k_gemm<384, 0><<<dim3(12, 64), 256, 0, stream>>>(Ax_hi, Ax_lo, Wi_hi, Wi_lo, xin, szT);
    k_conv<<<dim3(24, 32, NB), 256, 0, stream>>>(xin, conv_w, conv_b, u_hi, u_lo, uT);
    k_xprojm<<<NROWS / 64, 256, 0, stream>>>(u_hi, u_lo, Wx_hi, Wx_lo, dbc, bct);
    k_dtproj<<<dim3(12, NROWS / 64), 256, 0, stream>>>(dbc, dt_proj_w, dt_proj_b, dtyT);
    k_scan<<<dim3(D_INNER, NB), 1024, 0, stream>>>(dtyT, uT, szT, bct, A_log, Dp);
    k_splitT<<<dim3(24, 32, NB), 256, 0, stream>>>(dtyT, Ay_hi, Ay_lo, 768);
    k_gemm<768, 1><<<dim3(3, 64), 256, 0, stream>>>(Ay_hi, Ay_lo, Wo_hi, Wo_lo, out, nullptr);
}

// Round 6
// 353.135 us; speedup vs baseline: 3.3400x; 1.0136x over previous
//
#include <hip/hip_runtime.h>

#define D_MODEL 384
#define D_STATE 16
#define D_INNER 768
#define DT_RANK 24
#define NB 8
#define LSEQ 1024
#define NROWS (NB * LSEQ)             // 8192
#define DBC_N 56
#define SEG 16
#define NSEG 64

typedef unsigned short u16;
typedef __attribute__((ext_vector_type(8))) short bf16x8;
typedef __attribute__((ext_vector_type(4))) float f32x4;

__device__ __forceinline__ float silu(float x) { return x / (1.f + __expf(-x)); }

__device__ __forceinline__ u16 f2bf_rne(float v, float& hval) {
    unsigned u = __builtin_bit_cast(unsigned, v);
    unsigned h = (u + 0x7FFFu + ((u >> 16) & 1u)) >> 16;
    hval = __builtin_bit_cast(float, h << 16);
    return (u16)h;
}

__device__ __forceinline__ void split2(float v, u16& h, u16& l) {
    float hval, dummy;
    h = f2bf_rne(v, hval);
    l = f2bf_rne(v - hval, dummy);
}

// ---------------- weight split: f32 -> bf16 hi/lo
__global__ __launch_bounds__(256) void k_splitw(const float* __restrict__ src,
                                                u16* __restrict__ hi, u16* __restrict__ lo,
                                                int count) {
    const int i = blockIdx.x * 256 + threadIdx.x;
    if (i >= count) return;
    u16 h, l;
    split2(src[i], h, l);
    hi[i] = h; lo[i] = l;
}

// ---------------- x_proj weight split, padded 56 -> 64 rows (zeros)
__global__ __launch_bounds__(256) void k_splitw_pad(const float* __restrict__ src,
                                                    u16* __restrict__ hi, u16* __restrict__ lo) {
    const int i = blockIdx.x * 256 + threadIdx.x;   // over 64*768
    if (i >= 64 * 768) return;
    const int row = i / 768;
    u16 h = 0, l = 0;
    if (row < DBC_N) split2(src[i], h, l);
    hi[i] = h; lo[i] = l;
}

// ---------------- activation split + transpose: src [B][R][1024] f32 -> hi/lo [B*1024][R] bf16
__global__ __launch_bounds__(256) void k_splitT(const float* __restrict__ src,
                                                u16* __restrict__ hi, u16* __restrict__ lo,
                                                int R) {
    __shared__ float s[32][33];
    const int r0 = blockIdx.x * 32, c0 = blockIdx.y * 32, b = blockIdx.z;
    const int t = threadIdx.x;
    const int cc = t & 31, rr = t >> 5;
#pragma unroll
    for (int p = 0; p < 4; ++p)
        s[rr + p * 8][cc] = src[((size_t)b * R + r0 + rr + p * 8) * LSEQ + c0 + cc];
    __syncthreads();
    const int rr2 = t & 31, cc2 = t >> 5;
#pragma unroll
    for (int p = 0; p < 4; ++p) {
        const int c = cc2 + p * 8;
        u16 h, l;
        split2(s[rr2][c], h, l);
        const size_t idx = ((size_t)b * LSEQ + c0 + c) * R + r0 + rr2;
        hi[idx] = h; lo[idx] = l;
    }
}

// ---------------- split-bf16 MFMA GEMM (128x128 tile), 3 segments.
// MODE 0: in_proj epilogue; MODE 1: out_proj epilogue
template <int K, int MODE>
__global__ __launch_bounds__(256) void k_gemm(const u16* __restrict__ Ahi,
                                              const u16* __restrict__ Alo,
                                              const u16* __restrict__ Bhi,
                                              const u16* __restrict__ Blo,
                                              float* __restrict__ out0,
                                              float* __restrict__ out1) {
    constexpr int KT = K / 32;
    constexpr int NT = 3 * KT;
    __shared__ u16 lA[2][512 * 8];
    __shared__ u16 lB[2][512 * 8];
    const int tid = threadIdx.x;
    const int n0 = blockIdx.x * 128;
    const int m0 = blockIdx.y * 128;

    bf16x8 ra[2], rb[2];
    auto load_tile = [&](int t) {
        const int s = t / KT;
        const int ko = (t - s * KT) * 32;
        const u16* Ab = (s < 2) ? Ahi : Alo;
        const u16* Bb = (s == 1) ? Blo : Bhi;
#pragma unroll
        for (int i = 0; i < 2; ++i) {
            const int slot = tid + 256 * i;
            ra[i] = *reinterpret_cast<const bf16x8*>(
                Ab + (size_t)(m0 + (slot & 127)) * K + ko + (slot >> 7) * 8);
            rb[i] = *reinterpret_cast<const bf16x8*>(
                Bb + (size_t)(n0 + (slot & 127)) * K + ko + (slot >> 7) * 8);
        }
    };
    auto write_tile = [&](int buf) {
#pragma unroll
        for (int i = 0; i < 2; ++i) {
            const int slot = tid + 256 * i;
            *reinterpret_cast<bf16x8*>(&lA[buf][slot * 8]) = ra[i];
            *reinterpret_cast<bf16x8*>(&lB[buf][slot * 8]) = rb[i];
        }
    };

    load_tile(0);
    write_tile(0);
    load_tile(1);

    const int lane = tid & 63, w = tid >> 6;
    const int wm = w >> 1, wn = w & 1;
    const int fr = lane & 15, g = lane >> 4;
    const int abase = (g * 128 + wm * 64 + fr) * 8;
    const int bbase = (g * 128 + wn * 64 + fr) * 8;

    f32x4 acc[4][4] = {};
    for (int t = 0; t < NT; ++t) {
        const int cur = t & 1;
        __syncthreads();
        bf16x8 a[4], b[4];
#pragma unroll
        for (int mi = 0; mi < 4; ++mi)
            a[mi] = *reinterpret_cast<const bf16x8*>(&lA[cur][abase + mi * 128]);
#pragma unroll
        for (int ni = 0; ni < 4; ++ni)
            b[ni] = *reinterpret_cast<const bf16x8*>(&lB[cur][bbase + ni * 128]);
#pragma unroll
        for (int mi = 0; mi < 4; ++mi)
#pragma unroll
            for (int ni = 0; ni < 4; ++ni)
                acc[mi][ni] = __builtin_amdgcn_mfma_f32_16x16x32_bf16(
                    a[mi], b[ni], acc[mi][ni], 0, 0, 0);
        if (t + 1 < NT) {
            __syncthreads();
            write_tile(cur ^ 1);
            if (t + 2 < NT) load_tile(t + 2);
        }
    }

    const int b_idx = m0 >> 10;
    const int l0b = m0 & 1023;
    if (MODE == 0) {
        if (n0 < D_INNER) {
#pragma unroll
            for (int mi = 0; mi < 4; ++mi) {
#pragma unroll
                for (int ni = 0; ni < 4; ++ni) {
                    const int m = m0 + wm * 64 + mi * 16 + (lane >> 4) * 4;
                    const int n = n0 + wn * 64 + ni * 16 + (lane & 15);
#pragma unroll
                    for (int j = 0; j < 4; ++j)
                        out0[(size_t)(m + j) * D_INNER + n] = acc[mi][ni][j];
                }
            }
        } else {
#pragma unroll
            for (int mi = 0; mi < 4; ++mi) {
#pragma unroll
                for (int ni = 0; ni < 4; ++ni) {
                    const int l = l0b + wm * 64 + mi * 16 + (lane >> 4) * 4;
                    const int d = (n0 - D_INNER) + wn * 64 + ni * 16 + (lane & 15);
                    float4 v = make_float4(silu(acc[mi][ni][0]), silu(acc[mi][ni][1]),
                                           silu(acc[mi][ni][2]), silu(acc[mi][ni][3]));
                    *reinterpret_cast<float4*>(
                        &out1[((size_t)b_idx * D_INNER + d) * LSEQ + l]) = v;
                }
            }
        }
    } else {
#pragma unroll
        for (int mi = 0; mi < 4; ++mi) {
#pragma unroll
            for (int ni = 0; ni < 4; ++ni) {
                const int l = l0b + wm * 64 + mi * 16 + (lane >> 4) * 4;
                const int n = n0 + wn * 64 + ni * 16 + (lane & 15);
                float4 v = make_float4(acc[mi][ni][0], acc[mi][ni][1],
                                       acc[mi][ni][2], acc[mi][ni][3]);
                *reinterpret_cast<float4*>(
                    &out0[((size_t)b_idx * D_MODEL + n) * LSEQ + l]) = v;
            }
        }
    }
}

// ---------------- x_proj MFMA GEMM: M=8192 (64-row tiles), N=64 (padded), K=768, 3 segments.
__global__ __launch_bounds__(256) void k_xprojm(const u16* __restrict__ Uhi,
                                                const u16* __restrict__ Ulo,
                                                const u16* __restrict__ Whi,
                                                const u16* __restrict__ Wlo,
                                                float* __restrict__ dbc,
                                                float* __restrict__ bct) {
    __shared__ u16 lA[2][64 * 32];
    __shared__ u16 lB[2][64 * 32];
    const int tid = threadIdx.x;
    const int m0 = blockIdx.x * 64;
    const int arow = tid >> 2, acol = (tid & 3) * 8;

    bf16x8 ra, rb;
    auto load_tile = [&](int t) {
        const int s = t / 24;
        const int ko = (t - s * 24) * 32;
        const u16* Ab = (s < 2) ? Uhi : Ulo;
        const u16* Bb = (s == 1) ? Wlo : Whi;
        ra = *reinterpret_cast<const bf16x8*>(Ab + (size_t)(m0 + arow) * D_INNER + ko + acol);
        rb = *reinterpret_cast<const bf16x8*>(Bb + (size_t)arow * D_INNER + ko + acol);
    };
    auto write_tile = [&](int buf) {
        *reinterpret_cast<bf16x8*>(&lA[buf][arow * 32 + acol]) = ra;
        *reinterpret_cast<bf16x8*>(&lB[buf][arow * 32 + acol]) = rb;
    };

    load_tile(0);
    write_tile(0);
    load_tile(1);

    const int lane = tid & 63, w = tid >> 6;
    const int fr = lane & 15, g = lane >> 4;
    f32x4 acc[4] = {};
    for (int t = 0; t < 72; ++t) {
        const int cur = t & 1;
        __syncthreads();
        bf16x8 a = *reinterpret_cast<const bf16x8*>(&lA[cur][(w * 16 + fr) * 32 + g * 8]);
        bf16x8 b[4];
#pragma unroll
        for (int ni = 0; ni < 4; ++ni)
            b[ni] = *reinterpret_cast<const bf16x8*>(&lB[cur][(ni * 16 + fr) * 32 + g * 8]);
#pragma unroll
        for (int ni = 0; ni < 4; ++ni)
            acc[ni] = __builtin_amdgcn_mfma_f32_16x16x32_bf16(a, b[ni], acc[ni], 0, 0, 0);
        if (t + 1 < 72) {
            __syncthreads();
            write_tile(cur ^ 1);
            if (t + 2 < 72) load_tile(t + 2);
        }
    }

    const int b_idx = m0 >> 10;
#pragma unroll
    for (int ni = 0; ni < 4; ++ni) {
        const int col = ni * 16 + fr;
#pragma unroll
        for (int j = 0; j < 4; ++j) {
            const int r = w * 16 + g * 4 + j;
            const float v = acc[ni][j];
            if (col < DT_RANK) {
                dbc[(size_t)(m0 + r) * DBC_N + col] = v;
            } else if (col < DBC_N) {
                bct[((size_t)b_idx * 32 + (col - DT_RANK)) * LSEQ + ((m0 & 1023) + r)] = v;
            }
        }
    }
}

// ---------------- conv (causal, 3 taps) + SiLU -> uT [b][d][l] f32 + u split bf16 row-major
__global__ __launch_bounds__(256) void k_conv(const float* __restrict__ xin,
                                              const float* __restrict__ cw,
                                              const float* __restrict__ cb,
                                              u16* __restrict__ u_hi,
                                              u16* __restrict__ u_lo,
                                              float* __restrict__ uT) {
    __shared__ float xs[34][32];
    __shared__ float us[32][33];
    const int d0 = blockIdx.x * 32;
    const int l0 = blockIdx.y * 32;
    const int b  = blockIdx.z;
    const int t = threadIdx.x;
    const int dd = t & 31, r = t >> 5;
    for (int rr = r; rr < 34; rr += 8) {
        const int l = l0 - 2 + rr;
        xs[rr][dd] = (l >= 0) ? xin[((size_t)b * LSEQ + l) * D_INNER + d0 + dd] : 0.f;
    }
    __syncthreads();
    const float w0 = cw[(d0 + dd) * 3 + 0], w1 = cw[(d0 + dd) * 3 + 1], w2 = cw[(d0 + dd) * 3 + 2];
    const float bv = cb[d0 + dd];
#pragma unroll
    for (int p = 0; p < 4; ++p) {
        const int li = r + p * 8;
        float acc = bv;
        acc = fmaf(xs[li + 0][dd], w0, acc);
        acc = fmaf(xs[li + 1][dd], w1, acc);
        acc = fmaf(xs[li + 2][dd], w2, acc);
        const float uv = silu(acc);
        u16 h, l;
        split2(uv, h, l);
        const size_t idx = ((size_t)b * LSEQ + l0 + li) * D_INNER + d0 + dd;
        u_hi[idx] = h; u_lo[idx] = l;
        us[li][dd] = uv;
    }
    __syncthreads();
    const int ll = t & 31, dg = t >> 5;
#pragma unroll
    for (int p = 0; p < 4; ++p) {
        const int dl = dg + p * 8;
        uT[((size_t)b * D_INNER + d0 + dl) * LSEQ + l0 + ll] = us[ll][dl];
    }
}

// ---------------- dt_proj (K=24) + softplus -> dtT[b][d][l] (transposed via LDS tile)
__global__ __launch_bounds__(256) void k_dtproj(const float* __restrict__ dbc,
                                                const float* __restrict__ W,
                                                const float* __restrict__ bias,
                                                float* __restrict__ dtT) {
    __shared__ float sd[64][25];
    __shared__ float sw[64][24];
    __shared__ float sb[64];
    const int d0 = blockIdx.x * 64;
    const int row0 = blockIdx.y * 64;
    const int b = row0 >> 10, lr0 = row0 & 1023;
    const int t = threadIdx.x;
    for (int e = t; e < 64 * 24; e += 256) {
        const int rl = e / 24, rr = e - rl * 24;
        sd[rl][rr] = dbc[(size_t)(row0 + rl) * DBC_N + rr];
        sw[rl][rr] = W[(size_t)(d0 + rl) * DT_RANK + rr];
    }
    if (t < 64) sb[t] = bias[d0 + t];
    __syncthreads();
    const int ll = t & 63, dg = t >> 6;
    for (int dd = 0; dd < 16; ++dd) {
        const int dl = dg * 16 + dd;
        float acc = sb[dl];
#pragma unroll
        for (int r = 0; r < DT_RANK; ++r) acc = fmaf(sd[ll][r], sw[dl][r], acc);
        const float v = (acc > 20.f) ? acc : log1pf(__expf(acc));
        dtT[((size_t)b * D_INNER + d0 + dl) * LSEQ + lr0 + ll] = v;
    }
}

// ---------------- block-parallel selective scan.
// Pass A caches dA[l]=exp(dt*A) in regs; P is a running product of dA.
// Pass C: h = fma(dA[l], h, dt*u*B) -- no exp recompute. Creg load deferred
// to overlap the segment-scan phase. Pb/Hb padded to 67 (bank spread).
__global__ __launch_bounds__(1024, 8) void k_scan(float* dtyT,
                                                  const float* __restrict__ uT,
                                                  const float* __restrict__ szT,
                                                  const float* __restrict__ bct,
                                                  const float* __restrict__ A_log,
                                                  const float* __restrict__ Dp) {
    __shared__ float dt_s[LSEQ], u_s[LSEQ], sz_s[LSEQ], y_s[LSEQ];
    __shared__ float Pb[2][16][NSEG + 3], Hb[2][16][NSEG + 3];
    const int t = threadIdx.x;
    const int d = blockIdx.x;
    const int b = blockIdx.y;
    const size_t base = ((size_t)b * D_INNER + d) * LSEQ;
    if (t < 256) {
        *reinterpret_cast<float4*>(&dt_s[t * 4]) =
            *reinterpret_cast<const float4*>(&dtyT[base + t * 4]);
    } else if (t < 512) {
        const int q = (t - 256) * 4;
        *reinterpret_cast<float4*>(&u_s[q]) = *reinterpret_cast<const float4*>(&uT[base + q]);
    } else if (t < 768) {
        const int q = (t - 512) * 4;
        *reinterpret_cast<float4*>(&sz_s[q]) = *reinterpret_cast<const float4*>(&szT[base + q]);
    }
    const int n = t & 15, seg = t >> 4;
    const float Aval = -__expf(A_log[d * D_STATE + n]);
    const float Dv = Dp[d];
    float Breg[SEG];
    {
        const size_t bb = ((size_t)b * 32 + n) * LSEQ + seg * SEG;
#pragma unroll
        for (int q = 0; q < SEG; q += 4)
            *reinterpret_cast<float4*>(&Breg[q]) = *reinterpret_cast<const float4*>(&bct[bb + q]);
    }
    __syncthreads();
    const int l0 = seg * SEG;
    // pass A: segment-local state + cached dA + running product P
    float dA[SEG];
    float h = 0.f, P = 1.f;
#pragma unroll
    for (int l = 0; l < SEG; ++l) {
        const float dtv = dt_s[l0 + l];
        const float a = __expf(dtv * Aval);
        dA[l] = a;
        h = fmaf(a, h, dtv * u_s[l0 + l] * Breg[l]);
        P *= a;
    }
    Pb[0][n][seg] = P;
    Hb[0][n][seg] = h;
    // deferred Creg load: latency hides under the scan phase below
    float Creg[SEG];
    {
        const size_t cc = ((size_t)b * 32 + 16 + n) * LSEQ + seg * SEG;
#pragma unroll
        for (int q = 0; q < SEG; q += 4)
            *reinterpret_cast<float4*>(&Creg[q]) = *reinterpret_cast<const float4*>(&bct[cc + q]);
    }
    __syncthreads();
    // inclusive Hillis-Steele scan over 64 segments
    int cur = 0;
#pragma unroll
    for (int off = 1; off < NSEG; off <<= 1) {
        float Pc = Pb[cur][n][seg], Hc = Hb[cur][n][seg];
        if (seg >= off) {
            const float Pl = Pb[cur][n][seg - off], Hl = Hb[cur][n][seg - off];
            Hc = fmaf(Hl, Pc, Hc);
            Pc = Pl * Pc;
        }
        Pb[cur ^ 1][n][seg] = Pc;
        Hb[cur ^ 1][n][seg] = Hc;
        cur ^= 1;
        __syncthreads();
    }
    // pass C: exact prefix, cached dA
    h = (seg == 0) ? 0.f : Hb[cur][n][seg - 1];
#pragma unroll
    for (int l = 0; l < SEG; ++l) {
        const float dtv = dt_s[l0 + l];
        const float u_v = u_s[l0 + l];
        h = fmaf(dA[l], h, dtv * u_v * Breg[l]);
        float p = h * Creg[l];
        p += __shfl_xor(p, 1);
        p += __shfl_xor(p, 2);
        p += __shfl_xor(p, 4);
        p += __shfl_xor(p, 8);
        if (n == 0)
            y_s[l0 + l] = fmaf(u_v, Dv, p) * sz_s[l0 + l];
    }
    __syncthreads();
    if (t < 256)
        *reinterpret_cast<float4*>(&dtyT[base + t * 4]) =
            *reinterpret_cast<const float4*>(&y_s[t * 4]);
}

extern "C" void kernel_launch(void* const* d_in, const int* in_sizes, int n_in,
                              void* d_out, int out_size, void* d_ws, size_t ws_size,
                              hipStream_t stream) {
    const float* x         = (const float*)d_in[0];
    const float* in_proj_w = (const float*)d_in[1];
    const float* conv_w    = (const float*)d_in[2];
    const float* conv_b    = (const float*)d_in[3];
    const float* x_proj_w  = (const float*)d_in[4];
    const float* dt_proj_w = (const float*)d_in[5];
    const float* dt_proj_b = (const float*)d_in[6];
    const float* A_log     = (const float*)d_in[7];
    const float* Dp        = (const float*)d_in[8];
    const float* out_proj_w= (const float*)d_in[9];
    float* out = (float*)d_out;

    const size_t SB = (size_t)NROWS * D_INNER * 4;   // 25.2 MB
    char* wsb = (char*)d_ws;
    float* xin   = (float*)(wsb);                    // R0: xin, then dtT/y
    float* szT   = (float*)(wsb + SB);               // R1
    u16*  u_hi   = (u16*)  (wsb + 2 * SB);           // R2: u split bf16
    u16*  u_lo   = u_hi + (size_t)NROWS * D_INNER;
    float* uT    = (float*)(wsb + 3 * SB);           // R3: Ax split, then uT, then Ay split
    float* dbc   = (float*)(wsb + 4 * SB);
    float* bct   = (float*)(wsb + 4 * SB + 1835008);
    u16*  Wi_hi  = (u16*) (wsb + 4 * SB + 1835008 + 1048576);
    u16*  Wi_lo  = Wi_hi + 1536 * 384;
    u16*  Wo_hi  = Wi_lo + 1536 * 384;
    u16*  Wo_lo  = Wo_hi + 384 * 768;
    u16*  Wx_hi  = Wo_lo + 384 * 768;
    u16*  Wx_lo  = Wx_hi + 64 * 768;
    u16*  Ax_hi  = (u16*)uT;                 // dead before conv writes uT
    u16*  Ax_lo  = Ax_hi + (size_t)NROWS * 384;
    u16*  Ay_hi  = (u16*)uT;                 // uT dead after scan
    u16*  Ay_lo  = Ay_hi + (size_t)NROWS * 768;
    float* dtyT  = xin;                      // xin dead after conv; dt then y in place

    k_splitw<<<(1536 * 384 + 255) / 256, 256, 0, stream>>>(in_proj_w, Wi_hi, Wi_lo, 1536 * 384);
    k_splitw<<<(384 * 768 + 255) / 256, 256, 0, stream>>>(out_proj_w, Wo_hi, Wo_lo, 384 * 768);
    k_splitw_pad<<<(64 * 768 + 255) / 256, 256, 0, stream>>>(x_proj_w, Wx_hi, Wx_lo);
    k_splitT<<<dim3(12, 32, NB), 256, 0, stream>>>(x, Ax_hi, Ax_lo, 384);
    k_gemm<384, 0><<<dim3(12, 64), 256, 0, stream>>>(Ax_hi, Ax_lo, Wi_hi, Wi_lo, xin, szT);
    k_conv<<<dim3(24, 32, NB), 256, 0, stream>>>(xin, conv_w, conv_b, u_hi, u_lo, uT);
    k_xprojm<<<NROWS / 64, 256, 0, stream>>>(u_hi, u_lo, Wx_hi, Wx_lo, dbc, bct);
    k_dtproj<<<dim3(12, NROWS / 64), 256, 0, stream>>>(dbc, dt_proj_w, dt_proj_b, dtyT);
    k_scan<<<dim3(D_INNER, NB), 1024, 0, stream>>>(dtyT, uT, szT, bct, A_log, Dp);
    k_splitT<<<dim3(24, 32, NB), 256, 0, stream>>>(dtyT, Ay_hi, Ay_lo, 768);
    k_gemm<768, 1><<<dim3(3, 64), 256, 0, stream>>>(Ay_hi, Ay_lo, Wo_hi, Wo_lo, out, nullptr);
}

// Round 7
// 314.982 us; speedup vs baseline: 3.7446x; 1.1211x over previous
//
#include <hip/hip_runtime.h>

#define D_MODEL 384
#define D_STATE 16
#define D_INNER 768
#define DT_RANK 24
#define NB 8
#define LSEQ 1024
#define NROWS (NB * LSEQ)             // 8192
#define DBC_N 56
#define SEG 16
#define NSEG 64

typedef unsigned short u16;
typedef __attribute__((ext_vector_type(8))) short bf16x8;
typedef __attribute__((ext_vector_type(4))) float f32x4;

__device__ __forceinline__ float silu(float x) { return x / (1.f + __expf(-x)); }

__device__ __forceinline__ u16 f2bf_rne(float v, float& hval) {
    unsigned u = __builtin_bit_cast(unsigned, v);
    unsigned h = (u + 0x7FFFu + ((u >> 16) & 1u)) >> 16;
    hval = __builtin_bit_cast(float, h << 16);
    return (u16)h;
}

__device__ __forceinline__ void split2(float v, u16& h, u16& l) {
    float hval, dummy;
    h = f2bf_rne(v, hval);
    l = f2bf_rne(v - hval, dummy);
}

// DPP move within rows of 16 lanes (VALU, no DS pipe). CTRL 0x120+N = row_ror:N.
template <int CTRL>
__device__ __forceinline__ float dpp_mov(float v) {
    return __builtin_bit_cast(float, __builtin_amdgcn_update_dpp(
        0, __builtin_bit_cast(int, v), CTRL, 0xf, 0xf, false));
}

// ---------------- weight split: f32 -> bf16 hi/lo
__global__ __launch_bounds__(256) void k_splitw(const float* __restrict__ src,
                                                u16* __restrict__ hi, u16* __restrict__ lo,
                                                int count) {
    const int i = blockIdx.x * 256 + threadIdx.x;
    if (i >= count) return;
    u16 h, l;
    split2(src[i], h, l);
    hi[i] = h; lo[i] = l;
}

// ---------------- x_proj weight split, padded 56 -> 64 rows (zeros)
__global__ __launch_bounds__(256) void k_splitw_pad(const float* __restrict__ src,
                                                    u16* __restrict__ hi, u16* __restrict__ lo) {
    const int i = blockIdx.x * 256 + threadIdx.x;   // over 64*768
    if (i >= 64 * 768) return;
    const int row = i / 768;
    u16 h = 0, l = 0;
    if (row < DBC_N) split2(src[i], h, l);
    hi[i] = h; lo[i] = l;
}

// ---------------- activation split + transpose: src [B][R][1024] f32 -> hi/lo [B*1024][R] bf16
__global__ __launch_bounds__(256) void k_splitT(const float* __restrict__ src,
                                                u16* __restrict__ hi, u16* __restrict__ lo,
                                                int R) {
    __shared__ float s[32][33];
    const int r0 = blockIdx.x * 32, c0 = blockIdx.y * 32, b = blockIdx.z;
    const int t = threadIdx.x;
    const int cc = t & 31, rr = t >> 5;
#pragma unroll
    for (int p = 0; p < 4; ++p)
        s[rr + p * 8][cc] = src[((size_t)b * R + r0 + rr + p * 8) * LSEQ + c0 + cc];
    __syncthreads();
    const int rr2 = t & 31, cc2 = t >> 5;
#pragma unroll
    for (int p = 0; p < 4; ++p) {
        const int c = cc2 + p * 8;
        u16 h, l;
        split2(s[rr2][c], h, l);
        const size_t idx = ((size_t)b * LSEQ + c0 + c) * R + r0 + rr2;
        hi[idx] = h; lo[idx] = l;
    }
}

// ---------------- split-bf16 MFMA GEMM (128x128 tile), 3 segments.
// MODE 0: in_proj epilogue; MODE 1: out_proj epilogue
template <int K, int MODE>
__global__ __launch_bounds__(256) void k_gemm(const u16* __restrict__ Ahi,
                                              const u16* __restrict__ Alo,
                                              const u16* __restrict__ Bhi,
                                              const u16* __restrict__ Blo,
                                              float* __restrict__ out0,
                                              float* __restrict__ out1) {
    constexpr int KT = K / 32;
    constexpr int NT = 3 * KT;
    __shared__ u16 lA[2][512 * 8];
    __shared__ u16 lB[2][512 * 8];
    const int tid = threadIdx.x;
    const int n0 = blockIdx.x * 128;
    const int m0 = blockIdx.y * 128;

    bf16x8 ra[2], rb[2];
    auto load_tile = [&](int t) {
        const int s = t / KT;
        const int ko = (t - s * KT) * 32;
        const u16* Ab = (s < 2) ? Ahi : Alo;
        const u16* Bb = (s == 1) ? Blo : Bhi;
#pragma unroll
        for (int i = 0; i < 2; ++i) {
            const int slot = tid + 256 * i;
            ra[i] = *reinterpret_cast<const bf16x8*>(
                Ab + (size_t)(m0 + (slot & 127)) * K + ko + (slot >> 7) * 8);
            rb[i] = *reinterpret_cast<const bf16x8*>(
                Bb + (size_t)(n0 + (slot & 127)) * K + ko + (slot >> 7) * 8);
        }
    };
    auto write_tile = [&](int buf) {
#pragma unroll
        for (int i = 0; i < 2; ++i) {
            const int slot = tid + 256 * i;
            *reinterpret_cast<bf16x8*>(&lA[buf][slot * 8]) = ra[i];
            *reinterpret_cast<bf16x8*>(&lB[buf][slot * 8]) = rb[i];
        }
    };

    load_tile(0);
    write_tile(0);
    load_tile(1);

    const int lane = tid & 63, w = tid >> 6;
    const int wm = w >> 1, wn = w & 1;
    const int fr = lane & 15, g = lane >> 4;
    const int abase = (g * 128 + wm * 64 + fr) * 8;
    const int bbase = (g * 128 + wn * 64 + fr) * 8;

    f32x4 acc[4][4] = {};
    for (int t = 0; t < NT; ++t) {
        const int cur = t & 1;
        __syncthreads();
        bf16x8 a[4], b[4];
#pragma unroll
        for (int mi = 0; mi < 4; ++mi)
            a[mi] = *reinterpret_cast<const bf16x8*>(&lA[cur][abase + mi * 128]);
#pragma unroll
        for (int ni = 0; ni < 4; ++ni)
            b[ni] = *reinterpret_cast<const bf16x8*>(&lB[cur][bbase + ni * 128]);
#pragma unroll
        for (int mi = 0; mi < 4; ++mi)
#pragma unroll
            for (int ni = 0; ni < 4; ++ni)
                acc[mi][ni] = __builtin_amdgcn_mfma_f32_16x16x32_bf16(
                    a[mi], b[ni], acc[mi][ni], 0, 0, 0);
        if (t + 1 < NT) {
            __syncthreads();
            write_tile(cur ^ 1);
            if (t + 2 < NT) load_tile(t + 2);
        }
    }

    const int b_idx = m0 >> 10;
    const int l0b = m0 & 1023;
    if (MODE == 0) {
        if (n0 < D_INNER) {
#pragma unroll
            for (int mi = 0; mi < 4; ++mi) {
#pragma unroll
                for (int ni = 0; ni < 4; ++ni) {
                    const int m = m0 + wm * 64 + mi * 16 + (lane >> 4) * 4;
                    const int n = n0 + wn * 64 + ni * 16 + (lane & 15);
#pragma unroll
                    for (int j = 0; j < 4; ++j)
                        out0[(size_t)(m + j) * D_INNER + n] = acc[mi][ni][j];
                }
            }
        } else {
#pragma unroll
            for (int mi = 0; mi < 4; ++mi) {
#pragma unroll
                for (int ni = 0; ni < 4; ++ni) {
                    const int l = l0b + wm * 64 + mi * 16 + (lane >> 4) * 4;
                    const int d = (n0 - D_INNER) + wn * 64 + ni * 16 + (lane & 15);
                    float4 v = make_float4(silu(acc[mi][ni][0]), silu(acc[mi][ni][1]),
                                           silu(acc[mi][ni][2]), silu(acc[mi][ni][3]));
                    *reinterpret_cast<float4*>(
                        &out1[((size_t)b_idx * D_INNER + d) * LSEQ + l]) = v;
                }
            }
        }
    } else {
#pragma unroll
        for (int mi = 0; mi < 4; ++mi) {
#pragma unroll
            for (int ni = 0; ni < 4; ++ni) {
                const int l = l0b + wm * 64 + mi * 16 + (lane >> 4) * 4;
                const int n = n0 + wn * 64 + ni * 16 + (lane & 15);
                float4 v = make_float4(acc[mi][ni][0], acc[mi][ni][1],
                                       acc[mi][ni][2], acc[mi][ni][3]);
                *reinterpret_cast<float4*>(
                    &out0[((size_t)b_idx * D_MODEL + n) * LSEQ + l]) = v;
            }
        }
    }
}

// ---------------- x_proj MFMA GEMM: M=8192 (64-row tiles), N=64 (padded), K=768, 3 segments.
__global__ __launch_bounds__(256) void k_xprojm(const u16* __restrict__ Uhi,
                                                const u16* __restrict__ Ulo,
                                                const u16* __restrict__ Whi,
                                                const u16* __restrict__ Wlo,
                                                float* __restrict__ dbc,
                                                float* __restrict__ bct) {
    __shared__ u16 lA[2][64 * 32];
    __shared__ u16 lB[2][64 * 32];
    const int tid = threadIdx.x;
    const int m0 = blockIdx.x * 64;
    const int arow = tid >> 2, acol = (tid & 3) * 8;

    bf16x8 ra, rb;
    auto load_tile = [&](int t) {
        const int s = t / 24;
        const int ko = (t - s * 24) * 32;
        const u16* Ab = (s < 2) ? Uhi : Ulo;
        const u16* Bb = (s == 1) ? Wlo : Whi;
        ra = *reinterpret_cast<const bf16x8*>(Ab + (size_t)(m0 + arow) * D_INNER + ko + acol);
        rb = *reinterpret_cast<const bf16x8*>(Bb + (size_t)arow * D_INNER + ko + acol);
    };
    auto write_tile = [&](int buf) {
        *reinterpret_cast<bf16x8*>(&lA[buf][arow * 32 + acol]) = ra;
        *reinterpret_cast<bf16x8*>(&lB[buf][arow * 32 + acol]) = rb;
    };

    load_tile(0);
    write_tile(0);
    load_tile(1);

    const int lane = tid & 63, w = tid >> 6;
    const int fr = lane & 15, g = lane >> 4;
    f32x4 acc[4] = {};
    for (int t = 0; t < 72; ++t) {
        const int cur = t & 1;
        __syncthreads();
        bf16x8 a = *reinterpret_cast<const bf16x8*>(&lA[cur][(w * 16 + fr) * 32 + g * 8]);
        bf16x8 b[4];
#pragma unroll
        for (int ni = 0; ni < 4; ++ni)
            b[ni] = *reinterpret_cast<const bf16x8*>(&lB[cur][(ni * 16 + fr) * 32 + g * 8]);
#pragma unroll
        for (int ni = 0; ni < 4; ++ni)
            acc[ni] = __builtin_amdgcn_mfma_f32_16x16x32_bf16(a, b[ni], acc[ni], 0, 0, 0);
        if (t + 1 < 72) {
            __syncthreads();
            write_tile(cur ^ 1);
            if (t + 2 < 72) load_tile(t + 2);
        }
    }

    const int b_idx = m0 >> 10;
#pragma unroll
    for (int ni = 0; ni < 4; ++ni) {
        const int col = ni * 16 + fr;
#pragma unroll
        for (int j = 0; j < 4; ++j) {
            const int r = w * 16 + g * 4 + j;
            const float v = acc[ni][j];
            if (col < DT_RANK) {
                dbc[(size_t)(m0 + r) * DBC_N + col] = v;
            } else if (col < DBC_N) {
                bct[((size_t)b_idx * 32 + (col - DT_RANK)) * LSEQ + ((m0 & 1023) + r)] = v;
            }
        }
    }
}

// ---------------- conv (causal, 3 taps) + SiLU -> uT [b][d][l] f32 + u split bf16 row-major
__global__ __launch_bounds__(256) void k_conv(const float* __restrict__ xin,
                                              const float* __restrict__ cw,
                                              const float* __restrict__ cb,
                                              u16* __restrict__ u_hi,
                                              u16* __restrict__ u_lo,
                                              float* __restrict__ uT) {
    __shared__ float xs[34][32];
    __shared__ float us[32][33];
    const int d0 = blockIdx.x * 32;
    const int l0 = blockIdx.y * 32;
    const int b  = blockIdx.z;
    const int t = threadIdx.x;
    const int dd = t & 31, r = t >> 5;
    for (int rr = r; rr < 34; rr += 8) {
        const int l = l0 - 2 + rr;
        xs[rr][dd] = (l >= 0) ? xin[((size_t)b * LSEQ + l) * D_INNER + d0 + dd] : 0.f;
    }
    __syncthreads();
    const float w0 = cw[(d0 + dd) * 3 + 0], w1 = cw[(d0 + dd) * 3 + 1], w2 = cw[(d0 + dd) * 3 + 2];
    const float bv = cb[d0 + dd];
#pragma unroll
    for (int p = 0; p < 4; ++p) {
        const int li = r + p * 8;
        float acc = bv;
        acc = fmaf(xs[li + 0][dd], w0, acc);
        acc = fmaf(xs[li + 1][dd], w1, acc);
        acc = fmaf(xs[li + 2][dd], w2, acc);
        const float uv = silu(acc);
        u16 h, l;
        split2(uv, h, l);
        const size_t idx = ((size_t)b * LSEQ + l0 + li) * D_INNER + d0 + dd;
        u_hi[idx] = h; u_lo[idx] = l;
        us[li][dd] = uv;
    }
    __syncthreads();
    const int ll = t & 31, dg = t >> 5;
#pragma unroll
    for (int p = 0; p < 4; ++p) {
        const int dl = dg + p * 8;
        uT[((size_t)b * D_INNER + d0 + dl) * LSEQ + l0 + ll] = us[ll][dl];
    }
}

// ---------------- dt_proj (K=24) + softplus -> dtT[b][d][l] (transposed via LDS tile)
__global__ __launch_bounds__(256) void k_dtproj(const float* __restrict__ dbc,
                                                const float* __restrict__ W,
                                                const float* __restrict__ bias,
                                                float* __restrict__ dtT) {
    __shared__ float sd[64][25];
    __shared__ float sw[64][24];
    __shared__ float sb[64];
    const int d0 = blockIdx.x * 64;
    const int row0 = blockIdx.y * 64;
    const int b = row0 >> 10, lr0 = row0 & 1023;
    const int t = threadIdx.x;
    for (int e = t; e < 64 * 24; e += 256) {
        const int rl = e / 24, rr = e - rl * 24;
        sd[rl][rr] = dbc[(size_t)(row0 + rl) * DBC_N + rr];
        sw[rl][rr] = W[(size_t)(d0 + rl) * DT_RANK + rr];
    }
    if (t < 64) sb[t] = bias[d0 + t];
    __syncthreads();
    const int ll = t & 63, dg = t >> 6;
    for (int dd = 0; dd < 16; ++dd) {
        const int dl = dg * 16 + dd;
        float acc = sb[dl];
#pragma unroll
        for (int r = 0; r < DT_RANK; ++r) acc = fmaf(sd[ll][r], sw[dl][r], acc);
        const float v = (acc > 20.f) ? acc : log1pf(__expf(acc));
        dtT[((size_t)b * D_INNER + d0 + dl) * LSEQ + lr0 + ll] = v;
    }
}

// ---------------- block-parallel selective scan, v3.
// Pass A: per-segment (P,H). Segment scan: IN-WAVE (wave w scans the 64
// segments of state n=w via shfl_up, no barriers). Pass C: n-reduction via
// DPP row_ror rotate-reduce (pure VALU, zero DS ops). 4 barriers total.
__global__ __launch_bounds__(1024, 8) void k_scan(float* dtyT,
                                                  const float* __restrict__ uT,
                                                  const float* __restrict__ szT,
                                                  const float* __restrict__ bct,
                                                  const float* __restrict__ A_log,
                                                  const float* __restrict__ Dp) {
    __shared__ float dt_s[LSEQ], u_s[LSEQ], sz_s[LSEQ], y_s[LSEQ];
    __shared__ float Pb[16][NSEG + 2], Hb[16][NSEG + 2];
    const int t = threadIdx.x;
    const int d = blockIdx.x;
    const int b = blockIdx.y;
    const size_t base = ((size_t)b * D_INNER + d) * LSEQ;
    if (t < 256) {
        *reinterpret_cast<float4*>(&dt_s[t * 4]) =
            *reinterpret_cast<const float4*>(&dtyT[base + t * 4]);
    } else if (t < 512) {
        const int q = (t - 256) * 4;
        *reinterpret_cast<float4*>(&u_s[q]) = *reinterpret_cast<const float4*>(&uT[base + q]);
    } else if (t < 768) {
        const int q = (t - 512) * 4;
        *reinterpret_cast<float4*>(&sz_s[q]) = *reinterpret_cast<const float4*>(&szT[base + q]);
    }
    const int n = t & 15, seg = t >> 4;
    const float Aval = -__expf(A_log[d * D_STATE + n]);
    const float Dv = Dp[d];
    float Breg[SEG];
    {
        const size_t bb = ((size_t)b * 32 + n) * LSEQ + seg * SEG;
#pragma unroll
        for (int q = 0; q < SEG; q += 4)
            *reinterpret_cast<float4*>(&Breg[q]) = *reinterpret_cast<const float4*>(&bct[bb + q]);
    }
    __syncthreads();
    const int l0 = seg * SEG;
    // pass A: segment-local transform (P, H)
    float h = 0.f, P = 1.f;
#pragma unroll
    for (int l = 0; l < SEG; ++l) {
        const float dtv = dt_s[l0 + l];
        const float a = __expf(dtv * Aval);
        h = fmaf(a, h, dtv * u_s[l0 + l] * Breg[l]);
        P *= a;
    }
    Pb[n][seg] = P;
    Hb[n][seg] = h;
    // deferred Creg load: latency hides under the scan phase below
    float Creg[SEG];
    {
        const size_t cc = ((size_t)b * 32 + 16 + n) * LSEQ + seg * SEG;
#pragma unroll
        for (int q = 0; q < SEG; q += 4)
            *reinterpret_cast<float4*>(&Creg[q]) = *reinterpret_cast<const float4*>(&bct[cc + q]);
    }
    __syncthreads();
    // in-wave inclusive scan: wave w owns state n=w, lane = segment index
    {
        const int w = t >> 6, lane = t & 63;
        float Pw = Pb[w][lane], Hw = Hb[w][lane];
#pragma unroll
        for (int off = 1; off < NSEG; off <<= 1) {
            const float Pp = __shfl_up(Pw, off);
            const float Hp = __shfl_up(Hw, off);
            if (lane >= off) {
                Hw = fmaf(Hp, Pw, Hw);
                Pw *= Pp;
            }
        }
        Hb[w][lane] = Hw;
    }
    __syncthreads();
    // pass C: exact prefix; n-reduce via DPP rotate within rows of 16
    h = (seg == 0) ? 0.f : Hb[n][seg - 1];
#pragma unroll
    for (int l = 0; l < SEG; ++l) {
        const float dtv = dt_s[l0 + l];
        const float u_v = u_s[l0 + l];
        const float a = __expf(dtv * Aval);
        h = fmaf(a, h, dtv * u_v * Breg[l]);
        float p = h * Creg[l];
        p += dpp_mov<0x128>(p);   // row_ror:8
        p += dpp_mov<0x124>(p);   // row_ror:4
        p += dpp_mov<0x122>(p);   // row_ror:2
        p += dpp_mov<0x121>(p);   // row_ror:1
        if (n == 0)
            y_s[l0 + l] = fmaf(u_v, Dv, p) * sz_s[l0 + l];
    }
    __syncthreads();
    if (t < 256)
        *reinterpret_cast<float4*>(&dtyT[base + t * 4]) =
            *reinterpret_cast<const float4*>(&y_s[t * 4]);
}

extern "C" void kernel_launch(void* const* d_in, const int* in_sizes, int n_in,
                              void* d_out, int out_size, void* d_ws, size_t ws_size,
                              hipStream_t stream) {
    const float* x         = (const float*)d_in[0];
    const float* in_proj_w = (const float*)d_in[1];
    const float* conv_w    = (const float*)d_in[2];
    const float* conv_b    = (const float*)d_in[3];
    const float* x_proj_w  = (const float*)d_in[4];
    const float* dt_proj_w = (const float*)d_in[5];
    const float* dt_proj_b = (const float*)d_in[6];
    const float* A_log     = (const float*)d_in[7];
    const float* Dp        = (const float*)d_in[8];
    const float* out_proj_w= (const float*)d_in[9];
    float* out = (float*)d_out;

    const size_t SB = (size_t)NROWS * D_INNER * 4;   // 25.2 MB
    char* wsb = (char*)d_ws;
    float* xin   = (float*)(wsb);                    // R0: xin, then dtT/y
    float* szT   = (float*)(wsb + SB);               // R1
    u16*  u_hi   = (u16*)  (wsb + 2 * SB);           // R2: u split bf16
    u16*  u_lo   = u_hi + (size_t)NROWS * D_INNER;
    float* uT    = (float*)(wsb + 3 * SB);           // R3: Ax split, then uT, then Ay split
    float* dbc   = (float*)(wsb + 4 * SB);
    float* bct   = (float*)(wsb + 4 * SB + 1835008);
    u16*  Wi_hi  = (u16*) (wsb + 4 * SB + 1835008 + 1048576);
    u16*  Wi_lo  = Wi_hi + 1536 * 384;
    u16*  Wo_hi  = Wi_lo + 1536 * 384;
    u16*  Wo_lo  = Wo_hi + 384 * 768;
    u16*  Wx_hi  = Wo_lo + 384 * 768;
    u16*  Wx_lo  = Wx_hi + 64 * 768;
    u16*  Ax_hi  = (u16*)uT;                 // dead before conv writes uT
    u16*  Ax_lo  = Ax_hi + (size_t)NROWS * 384;
    u16*  Ay_hi  = (u16*)uT;                 // uT dead after scan
    u16*  Ay_lo  = Ay_hi + (size_t)NROWS * 768;
    float* dtyT  = xin;                      // xin dead after conv; dt then y in place

    k_splitw<<<(1536 * 384 + 255) / 256, 256, 0, stream>>>(in_proj_w, Wi_hi, Wi_lo, 1536 * 384);
    k_splitw<<<(384 * 768 + 255) / 256, 256, 0, stream>>>(out_proj_w, Wo_hi, Wo_lo, 384 * 768);
    k_splitw_pad<<<(64 * 768 + 255) / 256, 256, 0, stream>>>(x_proj_w, Wx_hi, Wx_lo);
    k_splitT<<<dim3(12, 32, NB), 256, 0, stream>>>(x, Ax_hi, Ax_lo, 384);
    k_gemm<384, 0><<<dim3(12, 64), 256, 0, stream>>>(Ax_hi, Ax_lo, Wi_hi, Wi_lo, xin, szT);
    k_conv<<<dim3(24, 32, NB), 256, 0, stream>>>(xin, conv_w, conv_b, u_hi, u_lo, uT);
    k_xprojm<<<NROWS / 64, 256, 0, stream>>>(u_hi, u_lo, Wx_hi, Wx_lo, dbc, bct);
    k_dtproj<<<dim3(12, NROWS / 64), 256, 0, stream>>>(dbc, dt_proj_w, dt_proj_b, dtyT);
    k_scan<<<dim3(D_INNER, NB), 1024, 0, stream>>>(dtyT, uT, szT, bct, A_log, Dp);
    k_splitT<<<dim3(24, 32, NB), 256, 0, stream>>>(dtyT, Ay_hi, Ay_lo, 768);
    k_gemm<768, 1><<<dim3(3, 64), 256, 0, stream>>>(Ay_hi, Ay_lo, Wo_hi, Wo_lo, out, nullptr);
}